// Round 1
// baseline (636.973 us; speedup 1.0000x reference)
//
#include <hip/hip_runtime.h>
#include <stdint.h>

// ---------------- types ----------------
typedef __bf16 bf16x8 __attribute__((ext_vector_type(8)));
typedef float f32x4 __attribute__((ext_vector_type(4)));
typedef unsigned short u16x8 __attribute__((ext_vector_type(8)));
typedef unsigned short u16x4 __attribute__((ext_vector_type(4)));
typedef float fvec4 __attribute__((ext_vector_type(4)));

__device__ __forceinline__ unsigned short f2b(float f) {
  unsigned u = __builtin_bit_cast(unsigned, f);
  return (unsigned short)((u + 0x7fffu + ((u >> 16) & 1u)) >> 16);
}

__device__ __forceinline__ bf16x8 ldfrag(const unsigned short* p) {
  return __builtin_bit_cast(bf16x8, *(const u16x8*)p);
}

// CK-style global->LDS direct load (16B per lane; LDS dest = wave base + lane*16)
__device__ __forceinline__ void gload_lds16(const void* g, void* l) {
  auto gp = reinterpret_cast<const __attribute__((address_space(1))) void*>(
      reinterpret_cast<uintptr_t>(g));
  auto lp = reinterpret_cast<__attribute__((address_space(3))) void*>(
      reinterpret_cast<uintptr_t>(l));
  __builtin_amdgcn_global_load_lds(gp, lp, 16, 0, 0);
}

// ---------------- weight transpose+cast: W[K][N] f32 -> Wt[N][K] bf16 ----------------
__global__ void transpose_cast(const float* __restrict__ W, unsigned short* __restrict__ Wt,
                               int K, int N) {
  __shared__ float tile[32][33];
  const int n0 = blockIdx.x * 32, k0 = blockIdx.y * 32;
  const int tx = threadIdx.x, ty = threadIdx.y;  // (32,8)
#pragma unroll
  for (int j = 0; j < 4; ++j)
    tile[ty + j * 8][tx] = W[(size_t)(k0 + ty + j * 8) * N + n0 + tx];
  __syncthreads();
#pragma unroll
  for (int j = 0; j < 4; ++j)
    Wt[(size_t)(n0 + ty + j * 8) * K + k0 + tx] = f2b(tile[tx][ty + j * 8]);
}

// ---------------- LayerNorm: fp32 row(1024) -> bf16 ----------------
__global__ void ln_kernel(const float* __restrict__ X, const float* __restrict__ g,
                          const float* __restrict__ be, unsigned short* __restrict__ H) {
  const int row = (blockIdx.x * blockDim.x + threadIdx.x) >> 6;
  const int l = threadIdx.x & 63;
  const float* xr = X + (size_t)row * 1024;
  fvec4 v[4];
  float s = 0.f, sq = 0.f;
#pragma unroll
  for (int i = 0; i < 4; ++i) {
    v[i] = *(const fvec4*)(xr + i * 256 + l * 4);
#pragma unroll
    for (int j = 0; j < 4; ++j) { s += v[i][j]; sq += v[i][j] * v[i][j]; }
  }
#pragma unroll
  for (int off = 32; off >= 1; off >>= 1) {
    s += __shfl_xor(s, off);
    sq += __shfl_xor(sq, off);
  }
  const float mean = s * (1.f / 1024.f);
  const float var = sq * (1.f / 1024.f) - mean * mean;
  const float rstd = rsqrtf(var + 1e-5f);
#pragma unroll
  for (int i = 0; i < 4; ++i) {
    const int col = i * 256 + l * 4;
    fvec4 gg = *(const fvec4*)(g + col);
    fvec4 bb = *(const fvec4*)(be + col);
    u16x4 o;
#pragma unroll
    for (int j = 0; j < 4; ++j) o[j] = f2b((v[i][j] - mean) * rstd * gg[j] + bb[j]);
    *(u16x4*)(H + (size_t)row * 1024 + col) = o;
  }
}

// ---------------- GEMM: C[M][N] = A[M][K] @ Bt[N][K]^T  (+epilogue) ----------------
// EPI 0: bf16 out. EPI 1: +bias, ReLU, bf16 out. EPI 2: +bias +resid, f32 out.
template <int EPI>
__global__ __launch_bounds__(256, 2) void gemm_bt(
    const unsigned short* __restrict__ A, const unsigned short* __restrict__ Bt,
    const float* __restrict__ bias, const float* __restrict__ resid,
    float* __restrict__ Cf, unsigned short* __restrict__ Cb, int M, int N, int K) {
  __shared__ unsigned short As[128 * 64];
  __shared__ unsigned short Bs[128 * 64];
  const int tid = threadIdx.x;
  const int w = tid >> 6, l = tid & 63;
  const int wr = w >> 1, wc = w & 1;
  const int kg = l >> 4, fr = l & 15;
  const size_t am0 = (size_t)blockIdx.y * 128;
  const size_t bn0 = (size_t)blockIdx.x * 128;
  f32x4 acc[4][4];
#pragma unroll
  for (int m = 0; m < 4; ++m)
#pragma unroll
    for (int n = 0; n < 4; ++n) acc[m][n] = (f32x4){0.f, 0.f, 0.f, 0.f};

  for (int k0 = 0; k0 < K; k0 += 64) {
#pragma unroll
    for (int i = 0; i < 4; ++i) {
      const int chunk = i * 4 + w;              // 16 chunks of 512 elems (8 rows x 64)
      const int flat = chunk * 512 + l * 8;
      const int row = flat >> 6, col = flat & 63;
      gload_lds16(A + (am0 + row) * K + k0 + col, As + chunk * 512);
      gload_lds16(Bt + (bn0 + row) * K + k0 + col, Bs + chunk * 512);
    }
    __syncthreads();
#pragma unroll
    for (int kk = 0; kk < 2; ++kk) {
      bf16x8 af[4], bfr[4];
#pragma unroll
      for (int m = 0; m < 4; ++m) af[m] = ldfrag(As + (wr * 64 + m * 16 + fr) * 64 + kk * 32 + kg * 8);
#pragma unroll
      for (int n = 0; n < 4; ++n) bfr[n] = ldfrag(Bs + (wc * 64 + n * 16 + fr) * 64 + kk * 32 + kg * 8);
#pragma unroll
      for (int m = 0; m < 4; ++m)
#pragma unroll
        for (int n = 0; n < 4; ++n)
          acc[m][n] = __builtin_amdgcn_mfma_f32_16x16x32_bf16(af[m], bfr[n], acc[m][n], 0, 0, 0);
    }
    __syncthreads();
  }
  // epilogue: lane holds C[row0+r][col], row0 = .. + kg*4, col = .. + fr
#pragma unroll
  for (int m = 0; m < 4; ++m) {
    const size_t row0 = am0 + wr * 64 + m * 16 + kg * 4;
#pragma unroll
    for (int n = 0; n < 4; ++n) {
      const size_t col = bn0 + wc * 64 + n * 16 + fr;
      const float bv = (EPI >= 1) ? bias[col] : 0.f;
#pragma unroll
      for (int r = 0; r < 4; ++r) {
        const size_t idx = (row0 + r) * N + col;
        float v = acc[m][n][r] + bv;
        if (EPI == 1) v = fmaxf(v, 0.f);
        if (EPI == 2) {
          v += resid[idx];
          Cf[idx] = v;
        } else {
          Cb[idx] = f2b(v);
        }
      }
    }
  }
}

// ---------------- fused causal attention ----------------
// QKV[row=b*2048+t][3072]: q at h*64+d, k at 1024+h*64+d, v at 2048+h*64+d (bf16)
// out ATT[row][1024] bf16. Block: 64 q-rows (4 waves x 16), KV tiles of 32.
#define VSTR 40
__global__ __launch_bounds__(256, 2) void attn_kernel(const unsigned short* __restrict__ QKV,
                                                      unsigned short* __restrict__ ATT) {
  __shared__ unsigned short Vt[64 * VSTR];      // V^T tile: [d=64][s=32] padded
  __shared__ unsigned short Pl[4][16 * VSTR];   // per-wave P: [q=16][s=32] padded
  const int tid = threadIdx.x;
  const int w = tid >> 6, l = tid & 63;
  const int kg = l >> 4, fr = l & 15;
  const int qt = blockIdx.x;  // 0..31
  const int bh = blockIdx.y;  // 0..63
  const int b = bh >> 4, h = bh & 15;
  const int q0 = qt * 64 + w * 16;
  const size_t base = (size_t)b * 2048 * 3072;

  // Q fragments (B operand of S^T = K @ Q^T): lane holds Q[q0+fr][d = kk*32 + kg*8 + j]
  const unsigned short* qrow = QKV + base + (size_t)(q0 + fr) * 3072 + h * 64;
  const bf16x8 bq0 = ldfrag(qrow + kg * 8);
  const bf16x8 bq1 = ldfrag(qrow + 32 + kg * 8);

  f32x4 o[4];
#pragma unroll
  for (int nd = 0; nd < 4; ++nd) o[nd] = (f32x4){0.f, 0.f, 0.f, 0.f};
  float m_run = -1e30f, l_run = 0.f;

  const int s_end = qt * 64 + 64;
  for (int s0 = 0; s0 < s_end; s0 += 32) {
    __syncthreads();
    {  // stage V^T tile (32 s-rows x 64 d) -> Vt[d][s]
      const int sv = tid >> 3;
      const int d0 = (tid & 7) * 8;
      const unsigned short* vsrc = QKV + base + (size_t)(s0 + sv) * 3072 + 2048 + h * 64 + d0;
      u16x8 vv = *(const u16x8*)vsrc;
#pragma unroll
      for (int j = 0; j < 8; ++j) Vt[(d0 + j) * VSTR + sv] = vv[j];
    }
    __syncthreads();
    if (s0 <= q0 + 15) {  // wave-uniform: skip fully-masked tiles
      // S^T (32s x 16q) = K-rows (A) @ Q (B), accumulated over 2 d-slices
      f32x4 st[2];
#pragma unroll
      for (int sg = 0; sg < 2; ++sg) {
        const unsigned short* krow = QKV + base + (size_t)(s0 + sg * 16 + fr) * 3072 + 1024 + h * 64;
        const bf16x8 ka0 = ldfrag(krow + kg * 8);
        const bf16x8 ka1 = ldfrag(krow + 32 + kg * 8);
        st[sg] = (f32x4){0.f, 0.f, 0.f, 0.f};
        st[sg] = __builtin_amdgcn_mfma_f32_16x16x32_bf16(ka0, bq0, st[sg], 0, 0, 0);
        st[sg] = __builtin_amdgcn_mfma_f32_16x16x32_bf16(ka1, bq1, st[sg], 0, 0, 0);
      }
      // scale + causal mask; lane: q = q0+fr, s = s0 + sg*16 + kg*4 + r
      const int qg = q0 + fr;
      float vals[8];
      float tmax = -1e30f;
#pragma unroll
      for (int sg = 0; sg < 2; ++sg)
#pragma unroll
        for (int r = 0; r < 4; ++r) {
          const int sgl = s0 + sg * 16 + kg * 4 + r;
          float v = st[sg][r] * 0.125f;
          if (sgl > qg) v = -1e30f;
          vals[sg * 4 + r] = v;
          tmax = fmaxf(tmax, v);
        }
      tmax = fmaxf(tmax, __shfl_xor(tmax, 16));
      tmax = fmaxf(tmax, __shfl_xor(tmax, 32));
      const float m_new = fmaxf(m_run, tmax);
      const float alpha = __expf(m_run - m_new);
      float psum = 0.f;
      unsigned short pb[8];
#pragma unroll
      for (int i = 0; i < 8; ++i) {
        const float p = __expf(vals[i] - m_new);
        psum += p;
        pb[i] = f2b(p);
      }
      psum += __shfl_xor(psum, 16);
      psum += __shfl_xor(psum, 32);
      l_run = l_run * alpha + psum;
      m_run = m_new;
      // write P (bf16) to per-wave LDS: P[q=fr][s]
#pragma unroll
      for (int sg = 0; sg < 2; ++sg) {
        u16x4 pk;
#pragma unroll
        for (int r = 0; r < 4; ++r) pk[r] = pb[sg * 4 + r];
        *(u16x4*)(&Pl[w][fr * VSTR + sg * 16 + kg * 4]) = pk;
      }
      // rescale O accumulators (rows of O are kg*4+r, need alpha of that q-row)
      float al[4];
#pragma unroll
      for (int r = 0; r < 4; ++r) al[r] = __shfl(alpha, kg * 4 + r);
#pragma unroll
      for (int nd = 0; nd < 4; ++nd)
#pragma unroll
        for (int r = 0; r < 4; ++r) o[nd][r] *= al[r];
      // PV: O(16q x 64d) += P (A) @ V (B from Vt rows)
      const bf16x8 pa = ldfrag(&Pl[w][fr * VSTR + kg * 8]);
#pragma unroll
      for (int nd = 0; nd < 4; ++nd) {
        const bf16x8 vb = ldfrag(&Vt[(nd * 16 + fr) * VSTR + kg * 8]);
        o[nd] = __builtin_amdgcn_mfma_f32_16x16x32_bf16(pa, vb, o[nd], 0, 0, 0);
      }
    }
  }
  // epilogue: normalize and store
  float linv[4];
#pragma unroll
  for (int r = 0; r < 4; ++r) linv[r] = 1.f / __shfl(l_run, kg * 4 + r);
#pragma unroll
  for (int nd = 0; nd < 4; ++nd)
#pragma unroll
    for (int r = 0; r < 4; ++r) {
      const size_t row = (size_t)b * 2048 + q0 + kg * 4 + r;
      ATT[row * 1024 + h * 64 + nd * 16 + fr] = f2b(o[nd][r] * linv[r]);
    }
}

// ---------------- launch ----------------
extern "C" void kernel_launch(void* const* d_in, const int* in_sizes, int n_in, void* d_out,
                              int out_size, void* d_ws, size_t ws_size, hipStream_t stream) {
  const float* x = (const float*)d_in[0];
  const float* Wk = (const float*)d_in[1];
  const float* Wq = (const float*)d_in[2];
  const float* Wv = (const float*)d_in[3];
  const float* Wproj = (const float*)d_in[4];
  const float* bproj = (const float*)d_in[5];
  const float* W1 = (const float*)d_in[6];
  const float* b1 = (const float*)d_in[7];
  const float* W2 = (const float*)d_in[8];
  const float* b2 = (const float*)d_in[9];
  const float* g1 = (const float*)d_in[10];
  const float* beta1 = (const float*)d_in[11];
  const float* g2 = (const float*)d_in[12];
  const float* beta2 = (const float*)d_in[13];
  float* out = (float*)d_out;
  unsigned short* wsu = (unsigned short*)d_ws;

  const size_t o_qkvW = 0;                          // [3072][1024]
  const size_t o_projW = o_qkvW + 3072 * 1024;      // [1024][1024]
  const size_t o_W1 = o_projW + 1024 * 1024;        // [4096][1024]
  const size_t o_W2 = o_W1 + 4096 * 1024;           // [1024][4096]
  const size_t o_H = o_W2 + 1024 * 4096;            // [8192][1024]
  const size_t o_QKV = o_H + (size_t)8192 * 1024;   // [8192][3072]
  const size_t o_ATT = o_QKV + (size_t)8192 * 3072; // [8192][1024]
  const size_t o_FF1 = o_QKV;                       // [8192][4096] (reuses QKV+ATT)

  dim3 tpb(32, 8);
  transpose_cast<<<dim3(32, 32), tpb, 0, stream>>>(Wq, wsu + o_qkvW, 1024, 1024);
  transpose_cast<<<dim3(32, 32), tpb, 0, stream>>>(Wk, wsu + o_qkvW + 1024 * 1024, 1024, 1024);
  transpose_cast<<<dim3(32, 32), tpb, 0, stream>>>(Wv, wsu + o_qkvW + 2 * 1024 * 1024, 1024, 1024);
  transpose_cast<<<dim3(32, 32), tpb, 0, stream>>>(Wproj, wsu + o_projW, 1024, 1024);
  transpose_cast<<<dim3(128, 32), tpb, 0, stream>>>(W1, wsu + o_W1, 1024, 4096);
  transpose_cast<<<dim3(32, 128), tpb, 0, stream>>>(W2, wsu + o_W2, 4096, 1024);

  ln_kernel<<<2048, 256, 0, stream>>>(x, g1, beta1, wsu + o_H);

  gemm_bt<0><<<dim3(24, 64), 256, 0, stream>>>(wsu + o_H, wsu + o_qkvW, nullptr, nullptr,
                                               nullptr, wsu + o_QKV, 8192, 3072, 1024);

  attn_kernel<<<dim3(32, 64), 256, 0, stream>>>(wsu + o_QKV, wsu + o_ATT);

  gemm_bt<2><<<dim3(8, 64), 256, 0, stream>>>(wsu + o_ATT, wsu + o_projW, bproj, x, out,
                                              nullptr, 8192, 1024, 1024);

  ln_kernel<<<2048, 256, 0, stream>>>(out, g2, beta2, wsu + o_H);

  gemm_bt<1><<<dim3(32, 64), 256, 0, stream>>>(wsu + o_H, wsu + o_W1, b1, nullptr, nullptr,
                                               wsu + o_FF1, 8192, 4096, 1024);

  gemm_bt<2><<<dim3(8, 64), 256, 0, stream>>>(wsu + o_FF1, wsu + o_W2, b2, out, out, nullptr,
                                              8192, 1024, 4096);
}

// Round 2
// 439.573 us; speedup vs baseline: 1.4491x; 1.4491x over previous
//
#include <hip/hip_runtime.h>
#include <stdint.h>

// ---------------- types ----------------
typedef __bf16 bf16x8 __attribute__((ext_vector_type(8)));
typedef float f32x4 __attribute__((ext_vector_type(4)));
typedef unsigned short u16x8 __attribute__((ext_vector_type(8)));
typedef unsigned short u16x4 __attribute__((ext_vector_type(4)));
typedef float fvec4 __attribute__((ext_vector_type(4)));

__device__ __forceinline__ unsigned short f2b(float f) {
  unsigned u = __builtin_bit_cast(unsigned, f);
  return (unsigned short)((u + 0x7fffu + ((u >> 16) & 1u)) >> 16);
}

__device__ __forceinline__ bf16x8 ldfrag(const unsigned short* p) {
  return __builtin_bit_cast(bf16x8, *(const u16x8*)p);
}

// global->LDS direct load (16B per lane; LDS dest = wave base + lane*16)
__device__ __forceinline__ void gload_lds16(const void* g, void* l) {
  auto gp = reinterpret_cast<const __attribute__((address_space(1))) void*>(
      reinterpret_cast<uintptr_t>(g));
  auto lp = reinterpret_cast<__attribute__((address_space(3))) void*>(
      reinterpret_cast<uintptr_t>(l));
  __builtin_amdgcn_global_load_lds(gp, lp, 16, 0, 0);
}

// ---------------- weight transpose+cast: W[K][N] f32 -> Wt[N][K] bf16 ----------------
__global__ void transpose_cast(const float* __restrict__ W, unsigned short* __restrict__ Wt,
                               int K, int N) {
  __shared__ float tile[32][33];
  const int n0 = blockIdx.x * 32, k0 = blockIdx.y * 32;
  const int tx = threadIdx.x, ty = threadIdx.y;  // (32,8)
#pragma unroll
  for (int j = 0; j < 4; ++j)
    tile[ty + j * 8][tx] = W[(size_t)(k0 + ty + j * 8) * N + n0 + tx];
  __syncthreads();
#pragma unroll
  for (int j = 0; j < 4; ++j)
    Wt[(size_t)(n0 + ty + j * 8) * K + k0 + tx] = f2b(tile[tx][ty + j * 8]);
}

// ---------------- V transpose: QKV v-part -> VT[bh][d=64][t=2048] bf16 ----------------
__global__ void vtrans(const unsigned short* __restrict__ QKV, unsigned short* __restrict__ VT) {
  __shared__ unsigned short tile[64][65];  // 130B row stride -> 2-way bank alias (free)
  const int bh = blockIdx.y, b = bh >> 4, h = bh & 15;
  const int t0 = blockIdx.x * 64;
  const int tx = threadIdx.x, ty = threadIdx.y;  // (64,8)
#pragma unroll
  for (int j = 0; j < 8; ++j)
    tile[ty + j * 8][tx] =
        QKV[(size_t)(b * 2048 + t0 + ty + j * 8) * 3072 + 2048 + h * 64 + tx];
  __syncthreads();
#pragma unroll
  for (int j = 0; j < 8; ++j)
    VT[((size_t)bh * 64 + ty + j * 8) * 2048 + t0 + tx] = tile[tx][ty + j * 8];
}

// ---------------- LayerNorm: fp32 row(1024) -> bf16 ----------------
__global__ void ln_kernel(const float* __restrict__ X, const float* __restrict__ g,
                          const float* __restrict__ be, unsigned short* __restrict__ H) {
  const int row = (blockIdx.x * blockDim.x + threadIdx.x) >> 6;
  const int l = threadIdx.x & 63;
  const float* xr = X + (size_t)row * 1024;
  fvec4 v[4];
  float s = 0.f, sq = 0.f;
#pragma unroll
  for (int i = 0; i < 4; ++i) {
    v[i] = *(const fvec4*)(xr + i * 256 + l * 4);
#pragma unroll
    for (int j = 0; j < 4; ++j) { s += v[i][j]; sq += v[i][j] * v[i][j]; }
  }
#pragma unroll
  for (int off = 32; off >= 1; off >>= 1) {
    s += __shfl_xor(s, off);
    sq += __shfl_xor(sq, off);
  }
  const float mean = s * (1.f / 1024.f);
  const float var = sq * (1.f / 1024.f) - mean * mean;
  const float rstd = rsqrtf(var + 1e-5f);
#pragma unroll
  for (int i = 0; i < 4; ++i) {
    const int col = i * 256 + l * 4;
    fvec4 gg = *(const fvec4*)(g + col);
    fvec4 bb = *(const fvec4*)(be + col);
    u16x4 o;
#pragma unroll
    for (int j = 0; j < 4; ++j) o[j] = f2b((v[i][j] - mean) * rstd * gg[j] + bb[j]);
    *(u16x4*)(H + (size_t)row * 1024 + col) = o;
  }
}

// ---------------- GEMM: C[M][N] = A[M][K] @ Bt[N][K]^T  (+epilogue) ----------------
// EPI 0: bf16 out. EPI 1: +bias, ReLU, bf16 out. EPI 2: +bias +resid, f32 out.
template <int EPI>
__global__ __launch_bounds__(256, 2) void gemm_bt(
    const unsigned short* __restrict__ A, const unsigned short* __restrict__ Bt,
    const float* __restrict__ bias, const float* __restrict__ resid,
    float* __restrict__ Cf, unsigned short* __restrict__ Cb, int M, int N, int K) {
  __shared__ unsigned short As[128 * 64];
  __shared__ unsigned short Bs[128 * 64];
  const int tid = threadIdx.x;
  const int w = tid >> 6, l = tid & 63;
  const int wr = w >> 1, wc = w & 1;
  const int kg = l >> 4, fr = l & 15;
  const size_t am0 = (size_t)blockIdx.y * 128;
  const size_t bn0 = (size_t)blockIdx.x * 128;
  f32x4 acc[4][4];
#pragma unroll
  for (int m = 0; m < 4; ++m)
#pragma unroll
    for (int n = 0; n < 4; ++n) acc[m][n] = (f32x4){0.f, 0.f, 0.f, 0.f};

  for (int k0 = 0; k0 < K; k0 += 64) {
#pragma unroll
    for (int i = 0; i < 4; ++i) {
      const int chunk = i * 4 + w;              // 16 chunks of 512 elems (8 rows x 64)
      const int flat = chunk * 512 + l * 8;
      const int row = flat >> 6, col = flat & 63;
      gload_lds16(A + (am0 + row) * K + k0 + col, As + chunk * 512);
      gload_lds16(Bt + (bn0 + row) * K + k0 + col, Bs + chunk * 512);
    }
    __syncthreads();
#pragma unroll
    for (int kk = 0; kk < 2; ++kk) {
      bf16x8 af[4], bfr[4];
#pragma unroll
      for (int m = 0; m < 4; ++m) af[m] = ldfrag(As + (wr * 64 + m * 16 + fr) * 64 + kk * 32 + kg * 8);
#pragma unroll
      for (int n = 0; n < 4; ++n) bfr[n] = ldfrag(Bs + (wc * 64 + n * 16 + fr) * 64 + kk * 32 + kg * 8);
#pragma unroll
      for (int m = 0; m < 4; ++m)
#pragma unroll
        for (int n = 0; n < 4; ++n)
          acc[m][n] = __builtin_amdgcn_mfma_f32_16x16x32_bf16(af[m], bfr[n], acc[m][n], 0, 0, 0);
    }
    __syncthreads();
  }
  // epilogue: lane holds C[row0+r][col], row0 = .. + kg*4, col = .. + fr
#pragma unroll
  for (int m = 0; m < 4; ++m) {
    const size_t row0 = am0 + wr * 64 + m * 16 + kg * 4;
#pragma unroll
    for (int n = 0; n < 4; ++n) {
      const size_t col = bn0 + wc * 64 + n * 16 + fr;
      const float bv = (EPI >= 1) ? bias[col] : 0.f;
#pragma unroll
      for (int r = 0; r < 4; ++r) {
        const size_t idx = (row0 + r) * N + col;
        float v = acc[m][n][r] + bv;
        if (EPI == 1) v = fmaxf(v, 0.f);
        if (EPI == 2) {
          v += resid[idx];
          Cf[idx] = v;
        } else {
          Cb[idx] = f2b(v);
        }
      }
    }
  }
}

// ---------------- fused causal attention (barrier-free) ----------------
// QKV[row=b*2048+t][3072]: q at h*64+d, k at 1024+h*64+d (bf16)
// VT[bh][d=64][t=2048] bf16 (pre-transposed V).  out ATT[row][1024] bf16.
// Block: 128 q-rows (4 waves x 32). KV tiles of 32. No __syncthreads anywhere:
// V^T comes from global (L2-fits, m169 lesson), P goes through per-wave LDS
// (within-wave write->read, compiler inserts lgkmcnt wait).
#define PSTR 40  // 80B rows: 16B-aligned, 2-way bank alias only (free)
__global__ __launch_bounds__(256, 4) void attn_kernel(const unsigned short* __restrict__ QKV,
                                                      const unsigned short* __restrict__ VT,
                                                      unsigned short* __restrict__ ATT) {
  __shared__ unsigned short Pl[4][32 * PSTR];  // per-wave P tile [q=32][s=32]
  const int tid = threadIdx.x;
  const int w = tid >> 6, l = tid & 63;
  const int kg = l >> 4, fr = l & 15;
  const int bh = blockIdx.y;
  const int b = bh >> 4, h = bh & 15;
  // scrambled q-tile index: complement-paired so each CU's resident blocks
  // sum to ~constant causal work (dispatch is ~round-robin over 256 CUs)
  const int s16 = (int)((blockIdx.x + blockIdx.y) & 15);
  const int qt = ((blockIdx.y >> 4) & 1) ? (15 - s16) : s16;
  const int q0 = qt * 128 + w * 32;  // wave's 32 q-rows
  const size_t base = (size_t)b * 2048 * 3072;
  const unsigned short* vtb = VT + (size_t)bh * 64 * 2048;

  // Q fragments (B operand of S^T = K @ Q^T): lane holds Q[q0+qg*16+fr][c*32+kg*8+j]
  bf16x8 bq[2][2];
#pragma unroll
  for (int qg = 0; qg < 2; ++qg) {
    const unsigned short* qrow = QKV + base + (size_t)(q0 + qg * 16 + fr) * 3072 + h * 64;
#pragma unroll
    for (int c = 0; c < 2; ++c) bq[qg][c] = ldfrag(qrow + c * 32 + kg * 8);
  }

  f32x4 o[2][4];
#pragma unroll
  for (int qg = 0; qg < 2; ++qg)
#pragma unroll
    for (int nd = 0; nd < 4; ++nd) o[qg][nd] = (f32x4){0.f, 0.f, 0.f, 0.f};
  float m_run[2] = {-1e30f, -1e30f}, l_run[2] = {0.f, 0.f};

  const int s_end = q0 + 32;  // causal: last tile containing s <= q0+31
  for (int s0 = 0; s0 < s_end; s0 += 32) {
    // ---- S^T (32s x 32q) = K (A) @ Q^T (B), accumulated over 2 d-slices ----
    bf16x8 ka[2][2];
#pragma unroll
    for (int sg = 0; sg < 2; ++sg) {
      const unsigned short* krow =
          QKV + base + (size_t)(s0 + sg * 16 + fr) * 3072 + 1024 + h * 64;
      ka[sg][0] = ldfrag(krow + kg * 8);
      ka[sg][1] = ldfrag(krow + 32 + kg * 8);
    }
    // V^T fragments for this tile (B operand of PV), shared across qg
    bf16x8 vb[4];
#pragma unroll
    for (int nd = 0; nd < 4; ++nd)
      vb[nd] = ldfrag(vtb + (size_t)(nd * 16 + fr) * 2048 + s0 + kg * 8);

    f32x4 st[2][2];
#pragma unroll
    for (int sg = 0; sg < 2; ++sg)
#pragma unroll
      for (int qg = 0; qg < 2; ++qg) {
        st[sg][qg] = (f32x4){0.f, 0.f, 0.f, 0.f};
        st[sg][qg] = __builtin_amdgcn_mfma_f32_16x16x32_bf16(ka[sg][0], bq[qg][0], st[sg][qg], 0, 0, 0);
        st[sg][qg] = __builtin_amdgcn_mfma_f32_16x16x32_bf16(ka[sg][1], bq[qg][1], st[sg][qg], 0, 0, 0);
      }

    // ---- online softmax; lane covers q = q0+qg*16+fr, s = s0+sg*16+kg*4+r ----
#pragma unroll
    for (int qg = 0; qg < 2; ++qg) {
      const int qa = q0 + qg * 16 + fr;
      float vals[8];
      float tmax = -1e30f;
#pragma unroll
      for (int sg = 0; sg < 2; ++sg)
#pragma unroll
        for (int r = 0; r < 4; ++r) {
          const int sa = s0 + sg * 16 + kg * 4 + r;
          float v = st[sg][qg][r] * 0.125f;
          if (sa > qa) v = -1e30f;
          vals[sg * 4 + r] = v;
          tmax = fmaxf(tmax, v);
        }
      tmax = fmaxf(tmax, __shfl_xor(tmax, 16));
      tmax = fmaxf(tmax, __shfl_xor(tmax, 32));
      const float m_new = fmaxf(m_run[qg], tmax);
      const float alpha = __expf(m_run[qg] - m_new);
      float psum = 0.f;
      unsigned short pb[8];
#pragma unroll
      for (int i = 0; i < 8; ++i) {
        const float p = __expf(vals[i] - m_new);
        psum += p;
        pb[i] = f2b(p);
      }
      psum += __shfl_xor(psum, 16);
      psum += __shfl_xor(psum, 32);
      l_run[qg] = l_run[qg] * alpha + psum;
      m_run[qg] = m_new;
      // write P to per-wave LDS: Pl[q][s]
#pragma unroll
      for (int sg = 0; sg < 2; ++sg) {
        u16x4 pk;
#pragma unroll
        for (int r = 0; r < 4; ++r) pk[r] = pb[sg * 4 + r];
        *(u16x4*)(&Pl[w][(qg * 16 + fr) * PSTR + sg * 16 + kg * 4]) = pk;
      }
      // rescale O accumulators (o rows are q' = qg*16 + kg*4 + r)
      float al[4];
#pragma unroll
      for (int r = 0; r < 4; ++r) al[r] = __shfl(alpha, kg * 4 + r);
#pragma unroll
      for (int nd = 0; nd < 4; ++nd)
#pragma unroll
        for (int r = 0; r < 4; ++r) o[qg][nd][r] *= al[r];
    }

    // ---- PV: O[32q][64d] += P (A) @ V (B via V^T rows from global) ----
    bf16x8 pa[2];
#pragma unroll
    for (int qg = 0; qg < 2; ++qg)
      pa[qg] = ldfrag(&Pl[w][(qg * 16 + fr) * PSTR + kg * 8]);
#pragma unroll
    for (int nd = 0; nd < 4; ++nd)
#pragma unroll
      for (int qg = 0; qg < 2; ++qg)
        o[qg][nd] = __builtin_amdgcn_mfma_f32_16x16x32_bf16(pa[qg], vb[nd], o[qg][nd], 0, 0, 0);
  }

  // ---- epilogue: normalize and store ----
#pragma unroll
  for (int qg = 0; qg < 2; ++qg) {
    float linv[4];
#pragma unroll
    for (int r = 0; r < 4; ++r) linv[r] = 1.f / __shfl(l_run[qg], kg * 4 + r);
#pragma unroll
    for (int nd = 0; nd < 4; ++nd)
#pragma unroll
      for (int r = 0; r < 4; ++r) {
        const size_t row = (size_t)b * 2048 + q0 + qg * 16 + kg * 4 + r;
        ATT[row * 1024 + h * 64 + nd * 16 + fr] = f2b(o[qg][nd][r] * linv[r]);
      }
  }
}

// ---------------- launch ----------------
extern "C" void kernel_launch(void* const* d_in, const int* in_sizes, int n_in, void* d_out,
                              int out_size, void* d_ws, size_t ws_size, hipStream_t stream) {
  const float* x = (const float*)d_in[0];
  const float* Wk = (const float*)d_in[1];
  const float* Wq = (const float*)d_in[2];
  const float* Wv = (const float*)d_in[3];
  const float* Wproj = (const float*)d_in[4];
  const float* bproj = (const float*)d_in[5];
  const float* W1 = (const float*)d_in[6];
  const float* b1 = (const float*)d_in[7];
  const float* W2 = (const float*)d_in[8];
  const float* b2 = (const float*)d_in[9];
  const float* g1 = (const float*)d_in[10];
  const float* beta1 = (const float*)d_in[11];
  const float* g2 = (const float*)d_in[12];
  const float* beta2 = (const float*)d_in[13];
  float* out = (float*)d_out;
  unsigned short* wsu = (unsigned short*)d_ws;

  const size_t o_qkvW = 0;                          // [3072][1024]
  const size_t o_projW = o_qkvW + 3072 * 1024;      // [1024][1024]
  const size_t o_W1 = o_projW + 1024 * 1024;        // [4096][1024]
  const size_t o_W2 = o_W1 + 4096 * 1024;           // [1024][4096]
  const size_t o_H = o_W2 + 1024 * 4096;            // [8192][1024] (also VT during attn)
  const size_t o_QKV = o_H + (size_t)8192 * 1024;   // [8192][3072]
  const size_t o_ATT = o_QKV + (size_t)8192 * 3072; // [8192][1024]
  const size_t o_FF1 = o_QKV;                       // [8192][4096] (reuses QKV)
  const size_t o_VT = o_H;                          // [64][64][2048] = 8192*1024, H is dead then

  dim3 tpb(32, 8);
  transpose_cast<<<dim3(32, 32), tpb, 0, stream>>>(Wq, wsu + o_qkvW, 1024, 1024);
  transpose_cast<<<dim3(32, 32), tpb, 0, stream>>>(Wk, wsu + o_qkvW + 1024 * 1024, 1024, 1024);
  transpose_cast<<<dim3(32, 32), tpb, 0, stream>>>(Wv, wsu + o_qkvW + 2 * 1024 * 1024, 1024, 1024);
  transpose_cast<<<dim3(32, 32), tpb, 0, stream>>>(Wproj, wsu + o_projW, 1024, 1024);
  transpose_cast<<<dim3(128, 32), tpb, 0, stream>>>(W1, wsu + o_W1, 1024, 4096);
  transpose_cast<<<dim3(32, 128), tpb, 0, stream>>>(W2, wsu + o_W2, 4096, 1024);

  ln_kernel<<<2048, 256, 0, stream>>>(x, g1, beta1, wsu + o_H);

  gemm_bt<0><<<dim3(24, 64), 256, 0, stream>>>(wsu + o_H, wsu + o_qkvW, nullptr, nullptr,
                                               nullptr, wsu + o_QKV, 8192, 3072, 1024);

  vtrans<<<dim3(32, 64), dim3(64, 8), 0, stream>>>(wsu + o_QKV, wsu + o_VT);

  attn_kernel<<<dim3(16, 64), 256, 0, stream>>>(wsu + o_QKV, wsu + o_VT, wsu + o_ATT);

  gemm_bt<2><<<dim3(8, 64), 256, 0, stream>>>(wsu + o_ATT, wsu + o_projW, bproj, x, out,
                                              nullptr, 8192, 1024, 1024);

  ln_kernel<<<2048, 256, 0, stream>>>(out, g2, beta2, wsu + o_H);

  gemm_bt<1><<<dim3(32, 64), 256, 0, stream>>>(wsu + o_H, wsu + o_W1, b1, nullptr, nullptr,
                                               wsu + o_FF1, 8192, 4096, 1024);

  gemm_bt<2><<<dim3(8, 64), 256, 0, stream>>>(wsu + o_FF1, wsu + o_W2, b2, out, out, nullptr,
                                              8192, 1024, 4096);
}

// Round 3
// 405.820 us; speedup vs baseline: 1.5696x; 1.0832x over previous
//
#include <hip/hip_runtime.h>
#include <stdint.h>

// ---------------- types ----------------
typedef __bf16 bf16x8 __attribute__((ext_vector_type(8)));
typedef float f32x4 __attribute__((ext_vector_type(4)));
typedef unsigned short u16x8 __attribute__((ext_vector_type(8)));
typedef unsigned short u16x4 __attribute__((ext_vector_type(4)));
typedef float fvec4 __attribute__((ext_vector_type(4)));

__device__ __forceinline__ unsigned short f2b(float f) {
  unsigned u = __builtin_bit_cast(unsigned, f);
  return (unsigned short)((u + 0x7fffu + ((u >> 16) & 1u)) >> 16);
}

__device__ __forceinline__ bf16x8 ldfrag(const unsigned short* p) {
  return __builtin_bit_cast(bf16x8, *(const u16x8*)p);
}

// global->LDS direct load (16B per lane; LDS dest = wave base + lane*16)
__device__ __forceinline__ void gload_lds16(const void* g, void* l) {
  auto gp = reinterpret_cast<const __attribute__((address_space(1))) void*>(
      reinterpret_cast<uintptr_t>(g));
  auto lp = reinterpret_cast<__attribute__((address_space(3))) void*>(
      reinterpret_cast<uintptr_t>(l));
  __builtin_amdgcn_global_load_lds(gp, lp, 16, 0, 0);
}

// ---------------- weight transpose+cast: W[K][N] f32 -> Wt[N][K] bf16 ----------------
__global__ void transpose_cast(const float* __restrict__ W, unsigned short* __restrict__ Wt,
                               int K, int N) {
  __shared__ float tile[32][33];
  const int n0 = blockIdx.x * 32, k0 = blockIdx.y * 32;
  const int tx = threadIdx.x, ty = threadIdx.y;  // (32,8)
#pragma unroll
  for (int j = 0; j < 4; ++j)
    tile[ty + j * 8][tx] = W[(size_t)(k0 + ty + j * 8) * N + n0 + tx];
  __syncthreads();
#pragma unroll
  for (int j = 0; j < 4; ++j)
    Wt[(size_t)(n0 + ty + j * 8) * K + k0 + tx] = f2b(tile[tx][ty + j * 8]);
}

// ---------------- V transpose: QKV v-part -> VT[bh][d=64][t=2048] bf16 ----------------
__global__ void vtrans(const unsigned short* __restrict__ QKV, unsigned short* __restrict__ VT) {
  __shared__ unsigned short tile[64][65];
  const int bh = blockIdx.y, b = bh >> 4, h = bh & 15;
  const int t0 = blockIdx.x * 64;
  const int tx = threadIdx.x, ty = threadIdx.y;  // (64,8)
#pragma unroll
  for (int j = 0; j < 8; ++j)
    tile[ty + j * 8][tx] =
        QKV[(size_t)(b * 2048 + t0 + ty + j * 8) * 3072 + 2048 + h * 64 + tx];
  __syncthreads();
#pragma unroll
  for (int j = 0; j < 8; ++j)
    VT[((size_t)bh * 64 + ty + j * 8) * 2048 + t0 + tx] = tile[tx][ty + j * 8];
}

// ---------------- LayerNorm: fp32 row(1024) -> bf16 ----------------
__global__ void ln_kernel(const float* __restrict__ X, const float* __restrict__ g,
                          const float* __restrict__ be, unsigned short* __restrict__ H) {
  const int row = (blockIdx.x * blockDim.x + threadIdx.x) >> 6;
  const int l = threadIdx.x & 63;
  const float* xr = X + (size_t)row * 1024;
  fvec4 v[4];
  float s = 0.f, sq = 0.f;
#pragma unroll
  for (int i = 0; i < 4; ++i) {
    v[i] = *(const fvec4*)(xr + i * 256 + l * 4);
#pragma unroll
    for (int j = 0; j < 4; ++j) { s += v[i][j]; sq += v[i][j] * v[i][j]; }
  }
#pragma unroll
  for (int off = 32; off >= 1; off >>= 1) {
    s += __shfl_xor(s, off);
    sq += __shfl_xor(sq, off);
  }
  const float mean = s * (1.f / 1024.f);
  const float var = sq * (1.f / 1024.f) - mean * mean;
  const float rstd = rsqrtf(var + 1e-5f);
#pragma unroll
  for (int i = 0; i < 4; ++i) {
    const int col = i * 256 + l * 4;
    fvec4 gg = *(const fvec4*)(g + col);
    fvec4 bb = *(const fvec4*)(be + col);
    u16x4 o;
#pragma unroll
    for (int j = 0; j < 4; ++j) o[j] = f2b((v[i][j] - mean) * rstd * gg[j] + bb[j]);
    *(u16x4*)(H + (size_t)row * 1024 + col) = o;
  }
}

// ---------------- deep-pipelined GEMM: C[M][N] = A[M][K] @ Bt[N][K]^T ----------------
// BM=256, BK=32, per-wave output 128x64. NBUF-deep LDS ring, ONE raw s_barrier per
// K-tile, counted vmcnt (never 0 in steady state). LDS tiles XOR-swizzled
// (col ^= ((row>>1)&3)<<4) on BOTH the pre-swizzled global source and the ds_read.
// EPI 0: bf16 out. EPI 1: +bias, ReLU, bf16 out. EPI 2: +bias +resid, f32 out.
template <int BN, int NBUF, int NTHREADS, int EPI>
__global__ __launch_bounds__(NTHREADS, 2) void gemm8p(
    const unsigned short* __restrict__ A, const unsigned short* __restrict__ Bt,
    const float* __restrict__ bias, const float* __restrict__ resid,
    float* __restrict__ Cf, unsigned short* __restrict__ Cb, int M, int N, int K) {
  constexpr int BM = 256, BK = 32;
  constexpr int ASZ = BM * BK * 2;                 // 16 KiB
  constexpr int BSZ = BN * BK * 2;                 // 16 or 8 KiB
  constexpr int BUFSZ = ASZ + BSZ;
  constexpr int NW = NTHREADS / 64;
  constexpr int WN = NW / 2;                       // waves along N
  constexpr int UA = ASZ / (NTHREADS * 16);
  constexpr int UB = BSZ / (NTHREADS * 16);
  constexpr int UNITS = UA + UB;
  constexpr int VMSTEADY = (NBUF - 2) * UNITS;
  static_assert(UA * NTHREADS * 16 == ASZ && UB * NTHREADS * 16 == BSZ, "unit split");
  __shared__ __align__(16) char lds[NBUF * BUFSZ];

  const int tid = threadIdx.x;
  const int w = tid >> 6, l = tid & 63;
  const int wr = w / WN, wc = w % WN;
  const int kg = l >> 4, fr = l & 15;

  // bijective XCD swizzle (all our grids are %8==0)
  const int gx = gridDim.x;
  const int wg0 = blockIdx.y * gx + blockIdx.x;
  const int q8 = (gx * gridDim.y) >> 3;
  const int swz = (wg0 & 7) * q8 + (wg0 >> 3);
  const size_t am0 = (size_t)(swz / gx) * BM;
  const size_t bn0 = (size_t)(swz % gx) * BN;

  // stage source pointers (pre-swizzled global col), kt = 0
  const char* src[UNITS];
#pragma unroll
  for (int u = 0; u < UA; ++u) {
    const int flatq = u * NTHREADS + tid;
    const int row = flatq >> 2;
    const int scb = ((flatq & 3) << 4) ^ (((row >> 1) & 3) << 4);
    src[u] = (const char*)(A + (am0 + row) * K) + scb;
  }
#pragma unroll
  for (int u = 0; u < UB; ++u) {
    const int flatq = u * NTHREADS + tid;
    const int row = flatq >> 2;
    const int scb = ((flatq & 3) << 4) ^ (((row >> 1) & 3) << 4);
    src[UA + u] = (const char*)(Bt + (bn0 + row) * K) + scb;
  }

  // swizzled ds_read byte offsets
  int Aoff[8], Boff[4];
#pragma unroll
  for (int m = 0; m < 8; ++m) {
    const int r = wr * 128 + m * 16 + fr;
    Aoff[m] = r * 64 + ((kg * 16) ^ (((r >> 1) & 3) << 4));
  }
#pragma unroll
  for (int n = 0; n < 4; ++n) {
    const int r = wc * 64 + n * 16 + fr;
    Boff[n] = ASZ + r * 64 + ((kg * 16) ^ (((r >> 1) & 3) << 4));
  }

  f32x4 acc[8][4];
#pragma unroll
  for (int m = 0; m < 8; ++m)
#pragma unroll
    for (int n = 0; n < 4; ++n) acc[m][n] = (f32x4){0.f, 0.f, 0.f, 0.f};

  auto stage = [&](int sb) {
#pragma unroll
    for (int u = 0; u < UNITS; ++u) {
      gload_lds16(src[u], lds + sb * BUFSZ + u * (NTHREADS * 16) + tid * 16);
      src[u] += 64;  // advance one K-tile (32 elems * 2B)
    }
  };

  const int NT = K / BK;
  // prologue: tiles 0..NBUF-2 in flight; wait until tile 0 landed
#pragma unroll
  for (int p = 0; p < NBUF - 1; ++p) stage(p);
  asm volatile("s_waitcnt vmcnt(%0)" ::"i"(VMSTEADY) : "memory");
  __builtin_amdgcn_s_barrier();

  int cb0 = 0, sb = NBUF - 1;
  for (int kt = 0; kt < NT; ++kt) {
    if (kt + NBUF - 1 < NT) stage(sb);
    bf16x8 af[8], bf[4];
#pragma unroll
    for (int m = 0; m < 8; ++m)
      af[m] = ldfrag((const unsigned short*)(lds + cb0 + Aoff[m]));
#pragma unroll
    for (int n = 0; n < 4; ++n)
      bf[n] = ldfrag((const unsigned short*)(lds + cb0 + Boff[n]));
    __builtin_amdgcn_s_setprio(1);
#pragma unroll
    for (int m = 0; m < 8; ++m)
#pragma unroll
      for (int n = 0; n < 4; ++n)
        acc[m][n] = __builtin_amdgcn_mfma_f32_16x16x32_bf16(af[m], bf[n], acc[m][n], 0, 0, 0);
    __builtin_amdgcn_s_setprio(0);
    // K-tile boundary: wait so tile kt+1 is fully landed (all waves), then barrier
    if (kt + NBUF - 1 < NT) {
      asm volatile("s_waitcnt vmcnt(%0)" ::"i"(VMSTEADY) : "memory");
      __builtin_amdgcn_s_barrier();
    } else if (kt + 2 < NT) {  // only reachable when NBUF==4
      asm volatile("s_waitcnt vmcnt(%0)" ::"i"(UNITS) : "memory");
      __builtin_amdgcn_s_barrier();
    } else if (kt + 1 < NT) {
      asm volatile("s_waitcnt vmcnt(0)" ::: "memory");
      __builtin_amdgcn_s_barrier();
    }
    cb0 += BUFSZ;
    if (cb0 == NBUF * BUFSZ) cb0 = 0;
    sb += 1;
    if (sb == NBUF) sb = 0;
  }

  // epilogue
#pragma unroll
  for (int m = 0; m < 8; ++m) {
    const size_t row0 = am0 + wr * 128 + m * 16 + kg * 4;
#pragma unroll
    for (int n = 0; n < 4; ++n) {
      const size_t col = bn0 + wc * 64 + n * 16 + fr;
      const float bv = (EPI >= 1) ? bias[col] : 0.f;
#pragma unroll
      for (int r = 0; r < 4; ++r) {
        const size_t idx = (row0 + r) * N + col;
        float v = acc[m][n][r] + bv;
        if (EPI == 1) v = fmaxf(v, 0.f);
        if (EPI == 2) {
          Cf[idx] = v + resid[idx];
        } else {
          Cb[idx] = f2b(v);
        }
      }
    }
  }
}

// ---------------- fused causal attention (barrier-free) ----------------
#define PSTR 40
__global__ __launch_bounds__(256, 4) void attn_kernel(const unsigned short* __restrict__ QKV,
                                                      const unsigned short* __restrict__ VT,
                                                      unsigned short* __restrict__ ATT) {
  __shared__ unsigned short Pl[4][32 * PSTR];
  const int tid = threadIdx.x;
  const int w = tid >> 6, l = tid & 63;
  const int kg = l >> 4, fr = l & 15;
  const int bh = blockIdx.y;
  const int b = bh >> 4, h = bh & 15;
  const int s16 = (int)((blockIdx.x + blockIdx.y) & 15);
  const int qt = ((blockIdx.y >> 4) & 1) ? (15 - s16) : s16;
  const int q0 = qt * 128 + w * 32;
  const size_t base = (size_t)b * 2048 * 3072;
  const unsigned short* vtb = VT + (size_t)bh * 64 * 2048;

  bf16x8 bq[2][2];
#pragma unroll
  for (int qg = 0; qg < 2; ++qg) {
    const unsigned short* qrow = QKV + base + (size_t)(q0 + qg * 16 + fr) * 3072 + h * 64;
#pragma unroll
    for (int c = 0; c < 2; ++c) bq[qg][c] = ldfrag(qrow + c * 32 + kg * 8);
  }

  f32x4 o[2][4];
#pragma unroll
  for (int qg = 0; qg < 2; ++qg)
#pragma unroll
    for (int nd = 0; nd < 4; ++nd) o[qg][nd] = (f32x4){0.f, 0.f, 0.f, 0.f};
  float m_run[2] = {-1e30f, -1e30f}, l_run[2] = {0.f, 0.f};

  const int s_end = q0 + 32;
  for (int s0 = 0; s0 < s_end; s0 += 32) {
    bf16x8 ka[2][2];
#pragma unroll
    for (int sg = 0; sg < 2; ++sg) {
      const unsigned short* krow =
          QKV + base + (size_t)(s0 + sg * 16 + fr) * 3072 + 1024 + h * 64;
      ka[sg][0] = ldfrag(krow + kg * 8);
      ka[sg][1] = ldfrag(krow + 32 + kg * 8);
    }
    bf16x8 vb[4];
#pragma unroll
    for (int nd = 0; nd < 4; ++nd)
      vb[nd] = ldfrag(vtb + (size_t)(nd * 16 + fr) * 2048 + s0 + kg * 8);

    f32x4 st[2][2];
#pragma unroll
    for (int sg = 0; sg < 2; ++sg)
#pragma unroll
      for (int qg = 0; qg < 2; ++qg) {
        st[sg][qg] = (f32x4){0.f, 0.f, 0.f, 0.f};
        st[sg][qg] = __builtin_amdgcn_mfma_f32_16x16x32_bf16(ka[sg][0], bq[qg][0], st[sg][qg], 0, 0, 0);
        st[sg][qg] = __builtin_amdgcn_mfma_f32_16x16x32_bf16(ka[sg][1], bq[qg][1], st[sg][qg], 0, 0, 0);
      }

#pragma unroll
    for (int qg = 0; qg < 2; ++qg) {
      const int qa = q0 + qg * 16 + fr;
      float vals[8];
      float tmax = -1e30f;
#pragma unroll
      for (int sg = 0; sg < 2; ++sg)
#pragma unroll
        for (int r = 0; r < 4; ++r) {
          const int sa = s0 + sg * 16 + kg * 4 + r;
          float v = st[sg][qg][r] * 0.125f;
          if (sa > qa) v = -1e30f;
          vals[sg * 4 + r] = v;
          tmax = fmaxf(tmax, v);
        }
      tmax = fmaxf(tmax, __shfl_xor(tmax, 16));
      tmax = fmaxf(tmax, __shfl_xor(tmax, 32));
      const float m_new = fmaxf(m_run[qg], tmax);
      const float alpha = __expf(m_run[qg] - m_new);
      float psum = 0.f;
      unsigned short pb[8];
#pragma unroll
      for (int i = 0; i < 8; ++i) {
        const float p = __expf(vals[i] - m_new);
        psum += p;
        pb[i] = f2b(p);
      }
      psum += __shfl_xor(psum, 16);
      psum += __shfl_xor(psum, 32);
      l_run[qg] = l_run[qg] * alpha + psum;
      m_run[qg] = m_new;
#pragma unroll
      for (int sg = 0; sg < 2; ++sg) {
        u16x4 pk;
#pragma unroll
        for (int r = 0; r < 4; ++r) pk[r] = pb[sg * 4 + r];
        *(u16x4*)(&Pl[w][(qg * 16 + fr) * PSTR + sg * 16 + kg * 4]) = pk;
      }
      float al[4];
#pragma unroll
      for (int r = 0; r < 4; ++r) al[r] = __shfl(alpha, kg * 4 + r);
#pragma unroll
      for (int nd = 0; nd < 4; ++nd)
#pragma unroll
        for (int r = 0; r < 4; ++r) o[qg][nd][r] *= al[r];
    }

    bf16x8 pa[2];
#pragma unroll
    for (int qg = 0; qg < 2; ++qg)
      pa[qg] = ldfrag(&Pl[w][(qg * 16 + fr) * PSTR + kg * 8]);
#pragma unroll
    for (int nd = 0; nd < 4; ++nd)
#pragma unroll
      for (int qg = 0; qg < 2; ++qg)
        o[qg][nd] = __builtin_amdgcn_mfma_f32_16x16x32_bf16(pa[qg], vb[nd], o[qg][nd], 0, 0, 0);
  }

#pragma unroll
  for (int qg = 0; qg < 2; ++qg) {
    float linv[4];
#pragma unroll
    for (int r = 0; r < 4; ++r) linv[r] = 1.f / __shfl(l_run[qg], kg * 4 + r);
#pragma unroll
    for (int nd = 0; nd < 4; ++nd)
#pragma unroll
      for (int r = 0; r < 4; ++r) {
        const size_t row = (size_t)b * 2048 + q0 + qg * 16 + kg * 4 + r;
        ATT[row * 1024 + h * 64 + nd * 16 + fr] = f2b(o[qg][nd][r] * linv[r]);
      }
  }
}

// ---------------- launch ----------------
extern "C" void kernel_launch(void* const* d_in, const int* in_sizes, int n_in, void* d_out,
                              int out_size, void* d_ws, size_t ws_size, hipStream_t stream) {
  const float* x = (const float*)d_in[0];
  const float* Wk = (const float*)d_in[1];
  const float* Wq = (const float*)d_in[2];
  const float* Wv = (const float*)d_in[3];
  const float* Wproj = (const float*)d_in[4];
  const float* bproj = (const float*)d_in[5];
  const float* W1 = (const float*)d_in[6];
  const float* b1 = (const float*)d_in[7];
  const float* W2 = (const float*)d_in[8];
  const float* b2 = (const float*)d_in[9];
  const float* g1 = (const float*)d_in[10];
  const float* beta1 = (const float*)d_in[11];
  const float* g2 = (const float*)d_in[12];
  const float* beta2 = (const float*)d_in[13];
  float* out = (float*)d_out;
  unsigned short* wsu = (unsigned short*)d_ws;

  const size_t o_qkvW = 0;                          // [3072][1024]
  const size_t o_projW = o_qkvW + 3072 * 1024;      // [1024][1024]
  const size_t o_W1 = o_projW + 1024 * 1024;        // [4096][1024]
  const size_t o_W2 = o_W1 + 4096 * 1024;           // [1024][4096]
  const size_t o_H = o_W2 + 1024 * 4096;            // [8192][1024] (VT during attn)
  const size_t o_QKV = o_H + (size_t)8192 * 1024;   // [8192][3072]
  const size_t o_ATT = o_QKV + (size_t)8192 * 3072; // [8192][1024]
  const size_t o_FF1 = o_QKV;                       // [8192][4096] (reuses QKV)
  const size_t o_VT = o_H;

  dim3 tpb(32, 8);
  transpose_cast<<<dim3(32, 32), tpb, 0, stream>>>(Wq, wsu + o_qkvW, 1024, 1024);
  transpose_cast<<<dim3(32, 32), tpb, 0, stream>>>(Wk, wsu + o_qkvW + 1024 * 1024, 1024, 1024);
  transpose_cast<<<dim3(32, 32), tpb, 0, stream>>>(Wv, wsu + o_qkvW + 2 * 1024 * 1024, 1024, 1024);
  transpose_cast<<<dim3(32, 32), tpb, 0, stream>>>(Wproj, wsu + o_projW, 1024, 1024);
  transpose_cast<<<dim3(128, 32), tpb, 0, stream>>>(W1, wsu + o_W1, 1024, 4096);
  transpose_cast<<<dim3(32, 128), tpb, 0, stream>>>(W2, wsu + o_W2, 4096, 1024);

  ln_kernel<<<2048, 256, 0, stream>>>(x, g1, beta1, wsu + o_H);

  // QKV: M=8192 N=3072 K=1024, grid (12,32)=384 blocks
  gemm8p<256, 4, 512, 0><<<dim3(12, 32), 512, 0, stream>>>(
      wsu + o_H, wsu + o_qkvW, nullptr, nullptr, nullptr, wsu + o_QKV, 8192, 3072, 1024);

  vtrans<<<dim3(32, 64), dim3(64, 8), 0, stream>>>(wsu + o_QKV, wsu + o_VT);

  attn_kernel<<<dim3(16, 64), 256, 0, stream>>>(wsu + o_QKV, wsu + o_VT, wsu + o_ATT);

  // proj: M=8192 N=1024 K=1024, grid (8,32)=256 blocks
  gemm8p<128, 3, 256, 2><<<dim3(8, 32), 256, 0, stream>>>(
      wsu + o_ATT, wsu + o_projW, bproj, x, out, nullptr, 8192, 1024, 1024);

  ln_kernel<<<2048, 256, 0, stream>>>(out, g2, beta2, wsu + o_H);

  // FF1: M=8192 N=4096 K=1024, grid (16,32)=512 blocks
  gemm8p<256, 4, 512, 1><<<dim3(16, 32), 512, 0, stream>>>(
      wsu + o_H, wsu + o_W1, b1, nullptr, nullptr, wsu + o_FF1, 8192, 4096, 1024);

  // FF2: M=8192 N=1024 K=4096, grid (8,32)=256 blocks
  gemm8p<128, 3, 256, 2><<<dim3(8, 32), 256, 0, stream>>>(
      wsu + o_FF1, wsu + o_W2, b2, out, out, nullptr, 8192, 1024, 4096);
}

// Round 4
// 405.580 us; speedup vs baseline: 1.5705x; 1.0006x over previous
//
#include <hip/hip_runtime.h>
#include <stdint.h>

// ---------------- types ----------------
typedef __bf16 bf16x8 __attribute__((ext_vector_type(8)));
typedef float f32x4 __attribute__((ext_vector_type(4)));
typedef unsigned short u16x8 __attribute__((ext_vector_type(8)));
typedef unsigned short u16x4 __attribute__((ext_vector_type(4)));
typedef unsigned int u32x2 __attribute__((ext_vector_type(2)));
typedef float fvec4 __attribute__((ext_vector_type(4)));

__device__ __forceinline__ unsigned short f2b(float f) {
  unsigned u = __builtin_bit_cast(unsigned, f);
  return (unsigned short)((u + 0x7fffu + ((u >> 16) & 1u)) >> 16);
}

__device__ __forceinline__ bf16x8 ldfrag(const unsigned short* p) {
  return __builtin_bit_cast(bf16x8, *(const u16x8*)p);
}

__device__ __forceinline__ float fexp2(float x) {
  float r;
  asm("v_exp_f32 %0, %1" : "=v"(r) : "v"(x));
  return r;
}

__device__ __forceinline__ unsigned cvtpk(float a, float b) {
  unsigned r;
  asm("v_cvt_pk_bf16_f32 %0, %1, %2" : "=v"(r) : "v"(a), "v"(b));
  return r;
}

// global->LDS direct load (16B per lane; LDS dest = wave base + lane*16)
__device__ __forceinline__ void gload_lds16(const void* g, void* l) {
  auto gp = reinterpret_cast<const __attribute__((address_space(1))) void*>(
      reinterpret_cast<uintptr_t>(g));
  auto lp = reinterpret_cast<__attribute__((address_space(3))) void*>(
      reinterpret_cast<uintptr_t>(l));
  __builtin_amdgcn_global_load_lds(gp, lp, 16, 0, 0);
}

// ---------------- weight transpose+cast: W[K][N] f32 -> Wt[N][K] bf16 ----------------
__global__ void transpose_cast(const float* __restrict__ W, unsigned short* __restrict__ Wt,
                               int K, int N) {
  __shared__ float tile[32][33];
  const int n0 = blockIdx.x * 32, k0 = blockIdx.y * 32;
  const int tx = threadIdx.x, ty = threadIdx.y;  // (32,8)
#pragma unroll
  for (int j = 0; j < 4; ++j)
    tile[ty + j * 8][tx] = W[(size_t)(k0 + ty + j * 8) * N + n0 + tx];
  __syncthreads();
#pragma unroll
  for (int j = 0; j < 4; ++j)
    Wt[(size_t)(n0 + ty + j * 8) * K + k0 + tx] = f2b(tile[tx][ty + j * 8]);
}

// ---------------- LayerNorm: fp32 row(1024) -> bf16 ----------------
__global__ void ln_kernel(const float* __restrict__ X, const float* __restrict__ g,
                          const float* __restrict__ be, unsigned short* __restrict__ H) {
  const int row = (blockIdx.x * blockDim.x + threadIdx.x) >> 6;
  const int l = threadIdx.x & 63;
  const float* xr = X + (size_t)row * 1024;
  fvec4 v[4];
  float s = 0.f, sq = 0.f;
#pragma unroll
  for (int i = 0; i < 4; ++i) {
    v[i] = *(const fvec4*)(xr + i * 256 + l * 4);
#pragma unroll
    for (int j = 0; j < 4; ++j) { s += v[i][j]; sq += v[i][j] * v[i][j]; }
  }
#pragma unroll
  for (int off = 32; off >= 1; off >>= 1) {
    s += __shfl_xor(s, off);
    sq += __shfl_xor(sq, off);
  }
  const float mean = s * (1.f / 1024.f);
  const float var = sq * (1.f / 1024.f) - mean * mean;
  const float rstd = rsqrtf(var + 1e-5f);
#pragma unroll
  for (int i = 0; i < 4; ++i) {
    const int col = i * 256 + l * 4;
    fvec4 gg = *(const fvec4*)(g + col);
    fvec4 bb = *(const fvec4*)(be + col);
    u16x4 o;
#pragma unroll
    for (int j = 0; j < 4; ++j) o[j] = f2b((v[i][j] - mean) * rstd * gg[j] + bb[j]);
    *(u16x4*)(H + (size_t)row * 1024 + col) = o;
  }
}

// ---------------- persistent deep-pipelined GEMM ----------------
// C[M][N] = A[M][K] @ Bt[N][K]^T. BK=32. NBUF-deep LDS ring, one raw s_barrier
// per K-tile, counted vmcnt. XOR swizzle (col16 ^= ((row>>1)&3)<<4) both sides.
// EPI 0: bf16. 1: +bias ReLU bf16. 2: +bias +resid f32. 3: QKV split (Q,K bf16; V transposed).
template <int BM, int BN, int WM, int WN, int NBUF, int NTH, int EPI>
__global__ __launch_bounds__(NTH, 2) void gemm8p(
    const unsigned short* __restrict__ A, const unsigned short* __restrict__ Bt,
    const float* __restrict__ bias, const float* __restrict__ resid,
    float* __restrict__ Cf, unsigned short* __restrict__ Cb,
    unsigned short* __restrict__ pK, unsigned short* __restrict__ pVT,
    int M, int N, int K, int ntiles) {
  constexpr int BK = 32;
  constexpr int ASZ = BM * BK * 2;
  constexpr int BSZ = BN * BK * 2;
  constexpr int BUFSZ = ASZ + BSZ;
  constexpr int NW = NTH / 64;
  static_assert(WM * WN == NW, "wave grid");
  constexpr int MF = BM / (WM * 16);
  constexpr int NF = BN / (WN * 16);
  constexpr int UA = ASZ / (NTH * 16);
  constexpr int UB = BSZ / (NTH * 16);
  constexpr int UNITS = UA + UB;
  constexpr int VMSTEADY = (NBUF - 2) * UNITS;
  static_assert(UA * NTH * 16 == ASZ && UB * NTH * 16 == BSZ, "unit split");
  __shared__ __align__(16) char lds[NBUF * BUFSZ];

  const int tid = threadIdx.x;
  const int w = tid >> 6, l = tid & 63;
  const int wr = w / WN, wc = w % WN;
  const int kg = l >> 4, fr = l & 15;
  const int xtiles = N / BN;
  const int nblk = (int)gridDim.x;

  // swizzled ds_read byte offsets (tile-independent)
  int Aoff[MF], Boff[NF];
#pragma unroll
  for (int m = 0; m < MF; ++m) {
    const int r = wr * (MF * 16) + m * 16 + fr;
    Aoff[m] = r * 64 + ((kg * 16) ^ (((r >> 1) & 3) << 4));
  }
#pragma unroll
  for (int n = 0; n < NF; ++n) {
    const int r = wc * (NF * 16) + n * 16 + fr;
    Boff[n] = ASZ + r * 64 + ((kg * 16) ^ (((r >> 1) & 3) << 4));
  }

  for (int tl = (int)blockIdx.x; tl < ntiles; tl += nblk) {
    if (tl != (int)blockIdx.x) __builtin_amdgcn_s_barrier();
    // bijective XCD swizzle (ntiles % 8 == 0 for all our launches)
    const int q8 = ntiles >> 3;
    const int swz = (tl & 7) * q8 + (tl >> 3);
    const size_t am0 = (size_t)(swz / xtiles) * BM;
    const size_t bn0 = (size_t)(swz % xtiles) * BN;

    const char* src[UNITS];
#pragma unroll
    for (int u = 0; u < UA; ++u) {
      const int flatq = u * NTH + tid;
      const int row = flatq >> 2;
      const int scb = ((flatq & 3) << 4) ^ (((row >> 1) & 3) << 4);
      src[u] = (const char*)(A + (am0 + row) * K) + scb;
    }
#pragma unroll
    for (int u = 0; u < UB; ++u) {
      const int flatq = u * NTH + tid;
      const int row = flatq >> 2;
      const int scb = ((flatq & 3) << 4) ^ (((row >> 1) & 3) << 4);
      src[UA + u] = (const char*)(Bt + (bn0 + row) * K) + scb;
    }

    f32x4 acc[MF][NF];
#pragma unroll
    for (int m = 0; m < MF; ++m)
#pragma unroll
      for (int n = 0; n < NF; ++n) acc[m][n] = (f32x4){0.f, 0.f, 0.f, 0.f};

    auto stage = [&](int sb) {
#pragma unroll
      for (int u = 0; u < UNITS; ++u) {
        gload_lds16(src[u], lds + sb * BUFSZ + u * (NTH * 16) + tid * 16);
        src[u] += 64;
      }
    };

    const int NT = K / BK;
#pragma unroll
    for (int p = 0; p < NBUF - 1; ++p) stage(p);
    asm volatile("s_waitcnt vmcnt(%0)" ::"i"(VMSTEADY) : "memory");
    __builtin_amdgcn_s_barrier();

    int cb0 = 0, sb = NBUF - 1;
    for (int kt = 0; kt < NT; ++kt) {
      if (kt + NBUF - 1 < NT) stage(sb);
      bf16x8 af[MF], bf[NF];
#pragma unroll
      for (int m = 0; m < MF; ++m)
        af[m] = ldfrag((const unsigned short*)(lds + cb0 + Aoff[m]));
#pragma unroll
      for (int n = 0; n < NF; ++n)
        bf[n] = ldfrag((const unsigned short*)(lds + cb0 + Boff[n]));
      __builtin_amdgcn_s_setprio(1);
#pragma unroll
      for (int m = 0; m < MF; ++m)
#pragma unroll
        for (int n = 0; n < NF; ++n)
          acc[m][n] = __builtin_amdgcn_mfma_f32_16x16x32_bf16(af[m], bf[n], acc[m][n], 0, 0, 0);
      __builtin_amdgcn_s_setprio(0);
      if (kt + NBUF - 1 < NT) {
        asm volatile("s_waitcnt vmcnt(%0)" ::"i"(VMSTEADY) : "memory");
        __builtin_amdgcn_s_barrier();
      } else if (kt + 2 < NT) {  // reachable only when NBUF==4
        asm volatile("s_waitcnt vmcnt(%0)" ::"i"(UNITS) : "memory");
        __builtin_amdgcn_s_barrier();
      } else if (kt + 1 < NT) {
        asm volatile("s_waitcnt vmcnt(0)" ::: "memory");
        __builtin_amdgcn_s_barrier();
      }
      cb0 += BUFSZ;
      if (cb0 == NBUF * BUFSZ) cb0 = 0;
      sb += 1;
      if (sb == NBUF) sb = 0;
    }

    // epilogue
#pragma unroll
    for (int m = 0; m < MF; ++m) {
      const size_t row0 = am0 + wr * (MF * 16) + m * 16 + kg * 4;
#pragma unroll
      for (int n = 0; n < NF; ++n) {
        const size_t col = bn0 + wc * (NF * 16) + n * 16 + fr;
        if (EPI == 3) {
          if (bn0 < 1024) {
#pragma unroll
            for (int r = 0; r < 4; ++r) Cb[(row0 + r) * 1024 + col] = f2b(acc[m][n][r]);
          } else if (bn0 < 2048) {
#pragma unroll
            for (int r = 0; r < 4; ++r) pK[(row0 + r) * 1024 + col - 1024] = f2b(acc[m][n][r]);
          } else {
            const int c2 = (int)col - 2048;
            const int hh = c2 >> 6, dd = c2 & 63;
            const int bb = (int)(row0 >> 11), tt = (int)(row0 & 2047);
            u16x4 pv;
#pragma unroll
            for (int r = 0; r < 4; ++r) pv[r] = f2b(acc[m][n][r]);
            *(u16x4*)(pVT + (((size_t)bb * 16 + hh) * 64 + dd) * 2048 + tt) = pv;
          }
        } else {
          const float bv = (EPI >= 1) ? bias[col] : 0.f;
#pragma unroll
          for (int r = 0; r < 4; ++r) {
            const size_t idx = (row0 + r) * N + col;
            float v = acc[m][n][r] + bv;
            if (EPI == 1) v = fmaxf(v, 0.f);
            if (EPI == 2) {
              Cf[idx] = v + resid[idx];
            } else {
              Cb[idx] = f2b(v);
            }
          }
        }
      }
    }
  }
}

// ---------------- fused causal attention (barrier-free, prefetched) ----------------
// Qb/Kb: [8192][1024] bf16 (col h*64+d). VT: [bh][64][2048] bf16. ATT out [8192][1024].
// Block: 128 q-rows (4 waves x 32). K prefetched one 32-tile ahead; V loaded at
// phase top; log2-domain online softmax with defer-max; P via cvt_pk -> per-wave LDS.
#define PSTR 40
#define SC2 0.18033688f  /* 0.125 * log2(e) */
__global__ __launch_bounds__(256, 3) void attn_kernel(const unsigned short* __restrict__ Qb,
                                                      const unsigned short* __restrict__ Kb,
                                                      const unsigned short* __restrict__ VT,
                                                      unsigned short* __restrict__ ATT) {
  __shared__ unsigned short Pl[4][32 * PSTR];
  const int tid = threadIdx.x;
  const int w = tid >> 6, l = tid & 63;
  const int kg = l >> 4, fr = l & 15;
  const int bh = blockIdx.x;  // 0..63
  const int b = bh >> 4, h = bh & 15;
  const int qt = 15 - (int)blockIdx.y;  // longest tiles dispatch first
  const int q0 = qt * 128 + w * 32;
  const size_t rbase = (size_t)b * 2048;
  const unsigned short* vtb = VT + (size_t)bh * 64 * 2048;

  bf16x8 bq[2][2];
#pragma unroll
  for (int qg = 0; qg < 2; ++qg) {
    const unsigned short* qrow = Qb + (rbase + q0 + qg * 16 + fr) * 1024 + h * 64;
#pragma unroll
    for (int c = 0; c < 2; ++c) bq[qg][c] = ldfrag(qrow + c * 32 + kg * 8);
  }

  f32x4 o[2][4];
#pragma unroll
  for (int qg = 0; qg < 2; ++qg)
#pragma unroll
    for (int nd = 0; nd < 4; ++nd) o[qg][nd] = (f32x4){0.f, 0.f, 0.f, 0.f};
  float m_run2[2] = {-1e30f, -1e30f}, l_run[2] = {0.f, 0.f};

  auto loadK = [&](int s0, bf16x8 (&ka)[2][2]) {
#pragma unroll
    for (int sg = 0; sg < 2; ++sg) {
      const unsigned short* krow = Kb + (rbase + s0 + sg * 16 + fr) * 1024 + h * 64;
      ka[sg][0] = ldfrag(krow + kg * 8);
      ka[sg][1] = ldfrag(krow + 32 + kg * 8);
    }
  };

  auto process = [&](int s0, bf16x8 (&ka)[2][2]) {
    bf16x8 vb[4];
#pragma unroll
    for (int nd = 0; nd < 4; ++nd)
      vb[nd] = ldfrag(vtb + (size_t)(nd * 16 + fr) * 2048 + s0 + kg * 8);

    f32x4 st[2][2];
#pragma unroll
    for (int sg = 0; sg < 2; ++sg)
#pragma unroll
      for (int qg = 0; qg < 2; ++qg) {
        st[sg][qg] = (f32x4){0.f, 0.f, 0.f, 0.f};
        st[sg][qg] = __builtin_amdgcn_mfma_f32_16x16x32_bf16(ka[sg][0], bq[qg][0], st[sg][qg], 0, 0, 0);
        st[sg][qg] = __builtin_amdgcn_mfma_f32_16x16x32_bf16(ka[sg][1], bq[qg][1], st[sg][qg], 0, 0, 0);
      }

#pragma unroll
    for (int qg = 0; qg < 2; ++qg) {
      const int qa = q0 + qg * 16 + fr;
      float vals[8];
      float tmax = -1e30f;
#pragma unroll
      for (int sg = 0; sg < 2; ++sg)
#pragma unroll
        for (int r = 0; r < 4; ++r) {
          const int sa = s0 + sg * 16 + kg * 4 + r;
          float v = (sa > qa) ? -1e30f : st[sg][qg][r];
          vals[sg * 4 + r] = v;
          tmax = fmaxf(tmax, v);
        }
      tmax = fmaxf(tmax, __shfl_xor(tmax, 16));
      tmax = fmaxf(tmax, __shfl_xor(tmax, 32));
      const float tm2 = tmax * SC2;
      if (__any(tm2 > m_run2[qg] + 8.f)) {  // rescale path (rare after warmup)
        const float m_new2 = fmaxf(m_run2[qg], tm2);
        const float alpha = fexp2(m_run2[qg] - m_new2);
        m_run2[qg] = m_new2;
        l_run[qg] *= alpha;
        float al[4];
#pragma unroll
        for (int r = 0; r < 4; ++r) al[r] = __shfl(alpha, kg * 4 + r);
#pragma unroll
        for (int nd = 0; nd < 4; ++nd)
#pragma unroll
          for (int r = 0; r < 4; ++r) o[qg][nd][r] *= al[r];
      }
      const float nm2 = -m_run2[qg];
      float psum = 0.f;
      unsigned pk[4];
#pragma unroll
      for (int i = 0; i < 4; ++i) {
        const float p0 = fexp2(__builtin_fmaf(vals[2 * i], SC2, nm2));
        const float p1 = fexp2(__builtin_fmaf(vals[2 * i + 1], SC2, nm2));
        psum += p0 + p1;
        pk[i] = cvtpk(p0, p1);
      }
      psum += __shfl_xor(psum, 16);
      psum += __shfl_xor(psum, 32);
      l_run[qg] += psum;
      u32x2 w0 = {pk[0], pk[1]};
      u32x2 w1 = {pk[2], pk[3]};
      *(u32x2*)(&Pl[w][(qg * 16 + fr) * PSTR + kg * 4]) = w0;
      *(u32x2*)(&Pl[w][(qg * 16 + fr) * PSTR + 16 + kg * 4]) = w1;
    }

    bf16x8 pa[2];
#pragma unroll
    for (int qg = 0; qg < 2; ++qg)
      pa[qg] = ldfrag(&Pl[w][(qg * 16 + fr) * PSTR + kg * 8]);
#pragma unroll
    for (int nd = 0; nd < 4; ++nd)
#pragma unroll
      for (int qg = 0; qg < 2; ++qg)
        o[qg][nd] = __builtin_amdgcn_mfma_f32_16x16x32_bf16(pa[qg], vb[nd], o[qg][nd], 0, 0, 0);
  };

  bf16x8 kaA[2][2], kaB[2][2];
  loadK(0, kaA);
  const int nt = (q0 >> 5) + 1;
  for (int t = 0; t < nt; t += 2) {
    if (t + 1 < nt) loadK((t + 1) << 5, kaB);
    process(t << 5, kaA);
    if (t + 1 < nt) {
      if (t + 2 < nt) loadK((t + 2) << 5, kaA);
      process((t + 1) << 5, kaB);
    }
  }

#pragma unroll
  for (int qg = 0; qg < 2; ++qg) {
    const float li = __builtin_amdgcn_rcpf(l_run[qg]);
    float linv[4];
#pragma unroll
    for (int r = 0; r < 4; ++r) linv[r] = __shfl(li, kg * 4 + r);
#pragma unroll
    for (int nd = 0; nd < 4; ++nd)
#pragma unroll
      for (int r = 0; r < 4; ++r) {
        const size_t row = rbase + q0 + qg * 16 + kg * 4 + r;
        ATT[row * 1024 + h * 64 + nd * 16 + fr] = f2b(o[qg][nd][r] * linv[r]);
      }
  }
}

// ---------------- launch ----------------
extern "C" void kernel_launch(void* const* d_in, const int* in_sizes, int n_in, void* d_out,
                              int out_size, void* d_ws, size_t ws_size, hipStream_t stream) {
  const float* x = (const float*)d_in[0];
  const float* Wk = (const float*)d_in[1];
  const float* Wq = (const float*)d_in[2];
  const float* Wv = (const float*)d_in[3];
  const float* Wproj = (const float*)d_in[4];
  const float* bproj = (const float*)d_in[5];
  const float* W1 = (const float*)d_in[6];
  const float* b1 = (const float*)d_in[7];
  const float* W2 = (const float*)d_in[8];
  const float* b2 = (const float*)d_in[9];
  const float* g1 = (const float*)d_in[10];
  const float* beta1 = (const float*)d_in[11];
  const float* g2 = (const float*)d_in[12];
  const float* beta2 = (const float*)d_in[13];
  float* out = (float*)d_out;
  unsigned short* wsu = (unsigned short*)d_ws;

  const size_t o_qkvW = 0;                           // [3072][1024]
  const size_t o_projW = o_qkvW + 3072 * 1024;       // [1024][1024]
  const size_t o_W1 = o_projW + 1024 * 1024;         // [4096][1024]
  const size_t o_W2 = o_W1 + 4096 * 1024;            // [1024][4096]
  const size_t o_H = o_W2 + 1024 * 4096;             // [8192][1024]
  const size_t o_Q = o_H + (size_t)8192 * 1024;      // [8192][1024]
  const size_t o_K = o_Q + (size_t)8192 * 1024;      // [8192][1024]
  const size_t o_VT = o_K + (size_t)8192 * 1024;     // [64][64][2048]
  const size_t o_ATT = o_VT + (size_t)8192 * 1024;   // [8192][1024]
  const size_t o_FF1 = o_Q;                          // [8192][4096] (reuses Q,K,VT,ATT)

  dim3 tpb(32, 8);
  transpose_cast<<<dim3(32, 32), tpb, 0, stream>>>(Wq, wsu + o_qkvW, 1024, 1024);
  transpose_cast<<<dim3(32, 32), tpb, 0, stream>>>(Wk, wsu + o_qkvW + 1024 * 1024, 1024, 1024);
  transpose_cast<<<dim3(32, 32), tpb, 0, stream>>>(Wv, wsu + o_qkvW + 2 * 1024 * 1024, 1024, 1024);
  transpose_cast<<<dim3(32, 32), tpb, 0, stream>>>(Wproj, wsu + o_projW, 1024, 1024);
  transpose_cast<<<dim3(128, 32), tpb, 0, stream>>>(W1, wsu + o_W1, 1024, 4096);
  transpose_cast<<<dim3(32, 128), tpb, 0, stream>>>(W2, wsu + o_W2, 4096, 1024);

  ln_kernel<<<2048, 256, 0, stream>>>(x, g1, beta1, wsu + o_H);

  // QKV: 768 tiles (24x32) persistent over 512 blocks, EPI3 splits Q/K/V^T
  gemm8p<256, 128, 2, 2, 3, 256, 3><<<512, 256, 0, stream>>>(
      wsu + o_H, wsu + o_qkvW, nullptr, nullptr, nullptr, wsu + o_Q, wsu + o_K, wsu + o_VT,
      8192, 3072, 1024, 768);

  attn_kernel<<<dim3(64, 16), 256, 0, stream>>>(wsu + o_Q, wsu + o_K, wsu + o_VT, wsu + o_ATT);

  // proj: 256 tiles (8x32)
  gemm8p<256, 128, 2, 2, 3, 256, 2><<<256, 256, 0, stream>>>(
      wsu + o_ATT, wsu + o_projW, bproj, x, out, nullptr, nullptr, nullptr,
      8192, 1024, 1024, 256);

  ln_kernel<<<2048, 256, 0, stream>>>(out, g2, beta2, wsu + o_H);

  // FF1: 512 tiles (16x32)
  gemm8p<256, 256, 2, 4, 4, 512, 1><<<512, 512, 0, stream>>>(
      wsu + o_H, wsu + o_W1, b1, nullptr, nullptr, wsu + o_FF1, nullptr, nullptr,
      8192, 4096, 1024, 512);

  // FF2: 256 tiles (8x32), K=4096
  gemm8p<256, 128, 2, 2, 3, 256, 2><<<256, 256, 0, stream>>>(
      wsu + o_FF1, wsu + o_W2, b2, out, out, nullptr, nullptr, nullptr,
      8192, 1024, 4096, 256);
}

// Round 5
// 355.437 us; speedup vs baseline: 1.7921x; 1.1411x over previous
//
#include <hip/hip_runtime.h>
#include <stdint.h>

// ---------------- types ----------------
typedef __bf16 bf16x8 __attribute__((ext_vector_type(8)));
typedef float f32x4 __attribute__((ext_vector_type(4)));
typedef unsigned short u16x8 __attribute__((ext_vector_type(8)));
typedef unsigned short u16x4 __attribute__((ext_vector_type(4)));
typedef unsigned int u32x2 __attribute__((ext_vector_type(2)));
typedef float fvec4 __attribute__((ext_vector_type(4)));

__device__ __forceinline__ unsigned short f2b(float f) {
  unsigned u = __builtin_bit_cast(unsigned, f);
  return (unsigned short)((u + 0x7fffu + ((u >> 16) & 1u)) >> 16);
}

__device__ __forceinline__ bf16x8 ldfrag(const unsigned short* p) {
  return __builtin_bit_cast(bf16x8, *(const u16x8*)p);
}

__device__ __forceinline__ float fexp2(float x) {
  float r;
  asm("v_exp_f32 %0, %1" : "=v"(r) : "v"(x));
  return r;
}

__device__ __forceinline__ unsigned cvtpk(float a, float b) {
  unsigned r;
  asm("v_cvt_pk_bf16_f32 %0, %1, %2" : "=v"(r) : "v"(a), "v"(b));
  return r;
}

// global->LDS direct load (16B per lane; LDS dest = wave base + lane*16)
__device__ __forceinline__ void gload_lds16(const void* g, void* l) {
  auto gp = reinterpret_cast<const __attribute__((address_space(1))) void*>(
      reinterpret_cast<uintptr_t>(g));
  auto lp = reinterpret_cast<__attribute__((address_space(3))) void*>(
      reinterpret_cast<uintptr_t>(l));
  __builtin_amdgcn_global_load_lds(gp, lp, 16, 0, 0);
}

// ---------------- weight transpose+cast: W[K][N] f32 -> Wt[N][K] bf16 ----------------
__global__ void transpose_cast(const float* __restrict__ W, unsigned short* __restrict__ Wt,
                               int K, int N) {
  __shared__ float tile[32][33];
  const int n0 = blockIdx.x * 32, k0 = blockIdx.y * 32;
  const int tx = threadIdx.x, ty = threadIdx.y;  // (32,8)
#pragma unroll
  for (int j = 0; j < 4; ++j)
    tile[ty + j * 8][tx] = W[(size_t)(k0 + ty + j * 8) * N + n0 + tx];
  __syncthreads();
#pragma unroll
  for (int j = 0; j < 4; ++j)
    Wt[(size_t)(n0 + ty + j * 8) * K + k0 + tx] = f2b(tile[tx][ty + j * 8]);
}

// ---------------- LayerNorm: fp32 row(1024) -> bf16 ----------------
__global__ void ln_kernel(const float* __restrict__ X, const float* __restrict__ g,
                          const float* __restrict__ be, unsigned short* __restrict__ H) {
  const int row = (blockIdx.x * blockDim.x + threadIdx.x) >> 6;
  const int l = threadIdx.x & 63;
  const float* xr = X + (size_t)row * 1024;
  fvec4 v[4];
  float s = 0.f, sq = 0.f;
#pragma unroll
  for (int i = 0; i < 4; ++i) {
    v[i] = *(const fvec4*)(xr + i * 256 + l * 4);
#pragma unroll
    for (int j = 0; j < 4; ++j) { s += v[i][j]; sq += v[i][j] * v[i][j]; }
  }
#pragma unroll
  for (int off = 32; off >= 1; off >>= 1) {
    s += __shfl_xor(s, off);
    sq += __shfl_xor(sq, off);
  }
  const float mean = s * (1.f / 1024.f);
  const float var = sq * (1.f / 1024.f) - mean * mean;
  const float rstd = rsqrtf(var + 1e-5f);
#pragma unroll
  for (int i = 0; i < 4; ++i) {
    const int col = i * 256 + l * 4;
    fvec4 gg = *(const fvec4*)(g + col);
    fvec4 bb = *(const fvec4*)(be + col);
    u16x4 o;
#pragma unroll
    for (int j = 0; j < 4; ++j) o[j] = f2b((v[i][j] - mean) * rstd * gg[j] + bb[j]);
    *(u16x4*)(H + (size_t)row * 1024 + col) = o;
  }
}

// ---------------- persistent deep-pipelined GEMM ----------------
// C[M][N] = A[M][K] @ Bt[N][K]^T. BK=32. NBUF-deep LDS ring, one raw s_barrier
// per K-tile, counted vmcnt. XOR swizzle (col16 ^= ((row>>1)&3)<<4) both sides.
// EPI 0: bf16. 1: +bias ReLU bf16. 2: +bias +resid f32. 3: QKV split (Q,K bf16; V transposed).
template <int BM, int BN, int WM, int WN, int NBUF, int NTH, int EPI>
__global__ __launch_bounds__(NTH, 2) void gemm8p(
    const unsigned short* __restrict__ A, const unsigned short* __restrict__ Bt,
    const float* __restrict__ bias, const float* __restrict__ resid,
    float* __restrict__ Cf, unsigned short* __restrict__ Cb,
    unsigned short* __restrict__ pK, unsigned short* __restrict__ pVT,
    int M, int N, int K, int ntiles) {
  constexpr int BK = 32;
  constexpr int ASZ = BM * BK * 2;
  constexpr int BSZ = BN * BK * 2;
  constexpr int BUFSZ = ASZ + BSZ;
  constexpr int NW = NTH / 64;
  static_assert(WM * WN == NW, "wave grid");
  constexpr int MF = BM / (WM * 16);
  constexpr int NF = BN / (WN * 16);
  constexpr int UA = ASZ / (NTH * 16);
  constexpr int UB = BSZ / (NTH * 16);
  constexpr int UNITS = UA + UB;
  constexpr int VMSTEADY = (NBUF - 2) * UNITS;
  static_assert(UA * NTH * 16 == ASZ && UB * NTH * 16 == BSZ, "unit split");
  __shared__ __align__(16) char lds[NBUF * BUFSZ];

  const int tid = threadIdx.x;
  const int w = tid >> 6, l = tid & 63;
  const int wr = w / WN, wc = w % WN;
  const int kg = l >> 4, fr = l & 15;
  const int xtiles = N / BN;
  const int nblk = (int)gridDim.x;

  // swizzled ds_read byte offsets (tile-independent)
  int Aoff[MF], Boff[NF];
#pragma unroll
  for (int m = 0; m < MF; ++m) {
    const int r = wr * (MF * 16) + m * 16 + fr;
    Aoff[m] = r * 64 + ((kg * 16) ^ (((r >> 1) & 3) << 4));
  }
#pragma unroll
  for (int n = 0; n < NF; ++n) {
    const int r = wc * (NF * 16) + n * 16 + fr;
    Boff[n] = ASZ + r * 64 + ((kg * 16) ^ (((r >> 1) & 3) << 4));
  }

  for (int tl = (int)blockIdx.x; tl < ntiles; tl += nblk) {
    if (tl != (int)blockIdx.x) __builtin_amdgcn_s_barrier();
    // bijective XCD swizzle (ntiles % 8 == 0 for all our launches)
    const int q8 = ntiles >> 3;
    const int swz = (tl & 7) * q8 + (tl >> 3);
    const size_t am0 = (size_t)(swz / xtiles) * BM;
    const size_t bn0 = (size_t)(swz % xtiles) * BN;

    const char* src[UNITS];
#pragma unroll
    for (int u = 0; u < UA; ++u) {
      const int flatq = u * NTH + tid;
      const int row = flatq >> 2;
      const int scb = ((flatq & 3) << 4) ^ (((row >> 1) & 3) << 4);
      src[u] = (const char*)(A + (am0 + row) * K) + scb;
    }
#pragma unroll
    for (int u = 0; u < UB; ++u) {
      const int flatq = u * NTH + tid;
      const int row = flatq >> 2;
      const int scb = ((flatq & 3) << 4) ^ (((row >> 1) & 3) << 4);
      src[UA + u] = (const char*)(Bt + (bn0 + row) * K) + scb;
    }

    f32x4 acc[MF][NF];
#pragma unroll
    for (int m = 0; m < MF; ++m)
#pragma unroll
      for (int n = 0; n < NF; ++n) acc[m][n] = (f32x4){0.f, 0.f, 0.f, 0.f};

    auto stage = [&](int sb) {
#pragma unroll
      for (int u = 0; u < UNITS; ++u) {
        gload_lds16(src[u], lds + sb * BUFSZ + u * (NTH * 16) + tid * 16);
        src[u] += 64;
      }
    };

    const int NT = K / BK;
#pragma unroll
    for (int p = 0; p < NBUF - 1; ++p) stage(p);
    asm volatile("s_waitcnt vmcnt(%0)" ::"i"(VMSTEADY) : "memory");
    __builtin_amdgcn_s_barrier();

    int cb0 = 0, sb = NBUF - 1;
    for (int kt = 0; kt < NT; ++kt) {
      if (kt + NBUF - 1 < NT) stage(sb);
      bf16x8 af[MF], bf[NF];
#pragma unroll
      for (int m = 0; m < MF; ++m)
        af[m] = ldfrag((const unsigned short*)(lds + cb0 + Aoff[m]));
#pragma unroll
      for (int n = 0; n < NF; ++n)
        bf[n] = ldfrag((const unsigned short*)(lds + cb0 + Boff[n]));
      __builtin_amdgcn_s_setprio(1);
#pragma unroll
      for (int m = 0; m < MF; ++m)
#pragma unroll
        for (int n = 0; n < NF; ++n)
          acc[m][n] = __builtin_amdgcn_mfma_f32_16x16x32_bf16(af[m], bf[n], acc[m][n], 0, 0, 0);
      __builtin_amdgcn_s_setprio(0);
      if (kt + NBUF - 1 < NT) {
        asm volatile("s_waitcnt vmcnt(%0)" ::"i"(VMSTEADY) : "memory");
        __builtin_amdgcn_s_barrier();
      } else if (kt + 2 < NT) {  // reachable only when NBUF==4
        asm volatile("s_waitcnt vmcnt(%0)" ::"i"(UNITS) : "memory");
        __builtin_amdgcn_s_barrier();
      } else if (kt + 1 < NT) {
        asm volatile("s_waitcnt vmcnt(0)" ::: "memory");
        __builtin_amdgcn_s_barrier();
      }
      cb0 += BUFSZ;
      if (cb0 == NBUF * BUFSZ) cb0 = 0;
      sb += 1;
      if (sb == NBUF) sb = 0;
    }

    // epilogue
#pragma unroll
    for (int m = 0; m < MF; ++m) {
      const size_t row0 = am0 + wr * (MF * 16) + m * 16 + kg * 4;
#pragma unroll
      for (int n = 0; n < NF; ++n) {
        const size_t col = bn0 + wc * (NF * 16) + n * 16 + fr;
        if (EPI == 3) {
          if (bn0 < 1024) {
#pragma unroll
            for (int r = 0; r < 4; ++r) Cb[(row0 + r) * 1024 + col] = f2b(acc[m][n][r]);
          } else if (bn0 < 2048) {
#pragma unroll
            for (int r = 0; r < 4; ++r) pK[(row0 + r) * 1024 + col - 1024] = f2b(acc[m][n][r]);
          } else {
            const int c2 = (int)col - 2048;
            const int hh = c2 >> 6, dd = c2 & 63;
            const int bb = (int)(row0 >> 11), tt = (int)(row0 & 2047);
            u16x4 pv;
#pragma unroll
            for (int r = 0; r < 4; ++r) pv[r] = f2b(acc[m][n][r]);
            *(u16x4*)(pVT + (((size_t)bb * 16 + hh) * 64 + dd) * 2048 + tt) = pv;
          }
        } else {
          const float bv = (EPI >= 1) ? bias[col] : 0.f;
#pragma unroll
          for (int r = 0; r < 4; ++r) {
            const size_t idx = (row0 + r) * N + col;
            float v = acc[m][n][r] + bv;
            if (EPI == 1) v = fmaxf(v, 0.f);
            if (EPI == 2) {
              Cf[idx] = v + resid[idx];
            } else {
              Cb[idx] = f2b(v);
            }
          }
        }
      }
    }
  }
}

// ---------------- fused causal attention: LDS-staged K, counted-vmcnt pipeline ----------------
// Qb/Kb: [8192][1024] bf16 (col h*64+d). VT: [bh][64][2048] bf16. ATT out [8192][1024].
// Block: 4 waves x 32q = 128 q-rows. KV tile = 64. K staged in 3-deep LDS ring via
// global_load_lds (XOR-swizzled both sides), one raw s_barrier + vmcnt(2) per tile.
// V^T read from global into regs (issued before QK MFMAs). P via per-wave LDS (PSTR=72).
#define PSTR 72
#define SC2 0.18033688f  /* 0.125 * log2(e) */
__global__ __launch_bounds__(256, 3) void attn_kernel(const unsigned short* __restrict__ Qb,
                                                      const unsigned short* __restrict__ Kb,
                                                      const unsigned short* __restrict__ VT,
                                                      unsigned short* __restrict__ ATT) {
  __shared__ __align__(16) char ldsK[3 * 8192];          // 64s x 64d bf16 per buffer
  __shared__ __align__(16) unsigned short Pl[4][32 * PSTR];
  const int tid = threadIdx.x;
  const int w = tid >> 6, l = tid & 63;
  const int kg = l >> 4, fr = l & 15;
  const int bh = blockIdx.x;  // 0..63
  const int b = bh >> 4, h = bh & 15;
  const int qt = 15 - (int)blockIdx.y;  // longest blocks dispatch first
  const int q0 = qt * 128 + w * 32;
  const size_t rbase = (size_t)b * 2048;
  const unsigned short* vtb = VT + (size_t)bh * 64 * 2048;

  // K staging source: inverse-swizzled global address (rule: linear LDS dest +
  // pre-swizzled source + swizzled ds_read). Row stride in Kb = 2048 B.
  const int rowoff = tid >> 3;                        // 0..31 within a 32-row unit
  const int cbsw = ((tid & 7) * 16) ^ ((rowoff & 7) << 4);
  const char* ksrc = (const char*)(Kb + rbase * 1024 + h * 64) + (size_t)rowoff * 2048 + cbsw;

  // swizzled ds_read byte offsets for K fragments: row r = sg*16+fr, col = c*64+kg*16
  int koff[4][2];
#pragma unroll
  for (int sg = 0; sg < 4; ++sg)
#pragma unroll
    for (int c = 0; c < 2; ++c)
      koff[sg][c] = (sg * 16 + fr) * 128 + ((c * 64 + kg * 16) ^ ((fr & 7) << 4));

  // Q fragments (B operand of S^T = K @ Q^T)
  bf16x8 bq[2][2];
#pragma unroll
  for (int qg = 0; qg < 2; ++qg) {
    const unsigned short* qrow = Qb + (rbase + q0 + qg * 16 + fr) * 1024 + h * 64;
#pragma unroll
    for (int c = 0; c < 2; ++c) bq[qg][c] = ldfrag(qrow + c * 32 + kg * 8);
  }

  f32x4 o[2][4];
#pragma unroll
  for (int qg = 0; qg < 2; ++qg)
#pragma unroll
    for (int nd = 0; nd < 4; ++nd) o[qg][nd] = (f32x4){0.f, 0.f, 0.f, 0.f};
  float m_run2[2] = {-1e30f, -1e30f}, l_run[2] = {0.f, 0.f};

  auto stage = [&](int t, int sbuf) {
    gload_lds16(ksrc + (size_t)(t * 64) * 2048, ldsK + sbuf * 8192 + tid * 16);
    gload_lds16(ksrc + (size_t)(t * 64 + 32) * 2048, ldsK + sbuf * 8192 + 4096 + tid * 16);
  };

  auto compute = [&](int s0, int cbb) {
    if (s0 > q0 + 31) return;  // wave-uniform causal skip (still hits barriers outside)
    // V^T fragments: issue early, consumed ~after softmax
    bf16x8 vb[4][2];
#pragma unroll
    for (int nd = 0; nd < 4; ++nd)
#pragma unroll
      for (int ks = 0; ks < 2; ++ks)
        vb[nd][ks] = ldfrag(vtb + (size_t)(nd * 16 + fr) * 2048 + s0 + ks * 32 + kg * 8);

    // S^T (64s x 32q): K rows from LDS (swizzled), Q from regs
    f32x4 st[4][2];
#pragma unroll
    for (int sg = 0; sg < 4; ++sg) {
      const bf16x8 ka0 = ldfrag((const unsigned short*)(ldsK + cbb + koff[sg][0]));
      const bf16x8 ka1 = ldfrag((const unsigned short*)(ldsK + cbb + koff[sg][1]));
#pragma unroll
      for (int qg = 0; qg < 2; ++qg) {
        st[sg][qg] = (f32x4){0.f, 0.f, 0.f, 0.f};
        st[sg][qg] = __builtin_amdgcn_mfma_f32_16x16x32_bf16(ka0, bq[qg][0], st[sg][qg], 0, 0, 0);
        st[sg][qg] = __builtin_amdgcn_mfma_f32_16x16x32_bf16(ka1, bq[qg][1], st[sg][qg], 0, 0, 0);
      }
    }

#pragma unroll
    for (int qg = 0; qg < 2; ++qg) {
      const int qa = q0 + qg * 16 + fr;
      float vals[16];
      float tmax = -1e30f;
#pragma unroll
      for (int sg = 0; sg < 4; ++sg)
#pragma unroll
        for (int r = 0; r < 4; ++r) {
          const int sa = s0 + sg * 16 + kg * 4 + r;
          float v = (sa > qa) ? -1e30f : st[sg][qg][r];
          vals[sg * 4 + r] = v;
          tmax = fmaxf(tmax, v);
        }
      tmax = fmaxf(tmax, __shfl_xor(tmax, 16));
      tmax = fmaxf(tmax, __shfl_xor(tmax, 32));
      const float tm2 = tmax * SC2;
      if (__any(tm2 > m_run2[qg] + 8.f)) {  // rescale path (rare after warmup)
        const float m_new2 = fmaxf(m_run2[qg], tm2);
        const float alpha = fexp2(m_run2[qg] - m_new2);
        m_run2[qg] = m_new2;
        l_run[qg] *= alpha;
        float al[4];
#pragma unroll
        for (int r = 0; r < 4; ++r) al[r] = __shfl(alpha, kg * 4 + r);
#pragma unroll
        for (int nd = 0; nd < 4; ++nd)
#pragma unroll
          for (int r = 0; r < 4; ++r) o[qg][nd][r] *= al[r];
      }
      const float nm2 = -m_run2[qg];
      float psum = 0.f;
      unsigned pk[8];
#pragma unroll
      for (int i = 0; i < 8; ++i) {
        const float p0 = fexp2(__builtin_fmaf(vals[2 * i], SC2, nm2));
        const float p1 = fexp2(__builtin_fmaf(vals[2 * i + 1], SC2, nm2));
        psum += p0 + p1;
        pk[i] = cvtpk(p0, p1);
      }
      psum += __shfl_xor(psum, 16);
      psum += __shfl_xor(psum, 32);
      l_run[qg] += psum;
      // P row (64 s-elems): per sg an 8B chunk at sg*16 + kg*4
#pragma unroll
      for (int sg = 0; sg < 4; ++sg) {
        u32x2 w2 = {pk[2 * sg], pk[2 * sg + 1]};
        *(u32x2*)(&Pl[w][(qg * 16 + fr) * PSTR + sg * 16 + kg * 4]) = w2;
      }
    }

    // PV: O[32q][64d] += P @ V, K=64 over two 32-chunks
#pragma unroll
    for (int qg = 0; qg < 2; ++qg)
#pragma unroll
      for (int ks = 0; ks < 2; ++ks) {
        const bf16x8 pa = ldfrag(&Pl[w][(qg * 16 + fr) * PSTR + ks * 32 + kg * 8]);
#pragma unroll
        for (int nd = 0; nd < 4; ++nd)
          o[qg][nd] = __builtin_amdgcn_mfma_f32_16x16x32_bf16(pa, vb[nd][ks], o[qg][nd], 0, 0, 0);
      }
  };

  const int NT = 2 * qt + 2;
  stage(0, 0);
  stage(1, 1);
  asm volatile("s_waitcnt vmcnt(2)" ::: "memory");
  __builtin_amdgcn_s_barrier();
  int cb = 0, sb = 2;
  for (int t = 0; t < NT; ++t) {
    if (t + 2 < NT) stage(t + 2, sb);
    compute(t * 64, cb * 8192);
    if (t + 2 < NT) {
      asm volatile("s_waitcnt vmcnt(2)" ::: "memory");
      __builtin_amdgcn_s_barrier();
    } else if (t + 1 < NT) {
      asm volatile("s_waitcnt vmcnt(0)" ::: "memory");
      __builtin_amdgcn_s_barrier();
    }
    cb += 1; if (cb == 3) cb = 0;
    sb += 1; if (sb == 3) sb = 0;
  }

  // epilogue: normalize and store
#pragma unroll
  for (int qg = 0; qg < 2; ++qg) {
    const float li = __builtin_amdgcn_rcpf(l_run[qg]);
    float linv[4];
#pragma unroll
    for (int r = 0; r < 4; ++r) linv[r] = __shfl(li, kg * 4 + r);
#pragma unroll
    for (int nd = 0; nd < 4; ++nd)
#pragma unroll
      for (int r = 0; r < 4; ++r) {
        const size_t row = rbase + q0 + qg * 16 + kg * 4 + r;
        ATT[row * 1024 + h * 64 + nd * 16 + fr] = f2b(o[qg][nd][r] * linv[r]);
      }
  }
}

// ---------------- launch ----------------
extern "C" void kernel_launch(void* const* d_in, const int* in_sizes, int n_in, void* d_out,
                              int out_size, void* d_ws, size_t ws_size, hipStream_t stream) {
  const float* x = (const float*)d_in[0];
  const float* Wk = (const float*)d_in[1];
  const float* Wq = (const float*)d_in[2];
  const float* Wv = (const float*)d_in[3];
  const float* Wproj = (const float*)d_in[4];
  const float* bproj = (const float*)d_in[5];
  const float* W1 = (const float*)d_in[6];
  const float* b1 = (const float*)d_in[7];
  const float* W2 = (const float*)d_in[8];
  const float* b2 = (const float*)d_in[9];
  const float* g1 = (const float*)d_in[10];
  const float* beta1 = (const float*)d_in[11];
  const float* g2 = (const float*)d_in[12];
  const float* beta2 = (const float*)d_in[13];
  float* out = (float*)d_out;
  unsigned short* wsu = (unsigned short*)d_ws;

  const size_t o_qkvW = 0;                           // [3072][1024]
  const size_t o_projW = o_qkvW + 3072 * 1024;       // [1024][1024]
  const size_t o_W1 = o_projW + 1024 * 1024;         // [4096][1024]
  const size_t o_W2 = o_W1 + 4096 * 1024;            // [1024][4096]
  const size_t o_H = o_W2 + 1024 * 4096;             // [8192][1024]
  const size_t o_Q = o_H + (size_t)8192 * 1024;      // [8192][1024]
  const size_t o_K = o_Q + (size_t)8192 * 1024;      // [8192][1024]
  const size_t o_VT = o_K + (size_t)8192 * 1024;     // [64][64][2048]
  const size_t o_ATT = o_VT + (size_t)8192 * 1024;   // [8192][1024]
  const size_t o_FF1 = o_Q;                          // [8192][4096] (reuses Q,K,VT,ATT)

  dim3 tpb(32, 8);
  transpose_cast<<<dim3(32, 32), tpb, 0, stream>>>(Wq, wsu + o_qkvW, 1024, 1024);
  transpose_cast<<<dim3(32, 32), tpb, 0, stream>>>(Wk, wsu + o_qkvW + 1024 * 1024, 1024, 1024);
  transpose_cast<<<dim3(32, 32), tpb, 0, stream>>>(Wv, wsu + o_qkvW + 2 * 1024 * 1024, 1024, 1024);
  transpose_cast<<<dim3(32, 32), tpb, 0, stream>>>(Wproj, wsu + o_projW, 1024, 1024);
  transpose_cast<<<dim3(128, 32), tpb, 0, stream>>>(W1, wsu + o_W1, 1024, 4096);
  transpose_cast<<<dim3(32, 128), tpb, 0, stream>>>(W2, wsu + o_W2, 4096, 1024);

  ln_kernel<<<2048, 256, 0, stream>>>(x, g1, beta1, wsu + o_H);

  // QKV: 768 tiles (24x32) persistent over 512 blocks, EPI3 splits Q/K/V^T
  gemm8p<256, 128, 2, 2, 3, 256, 3><<<512, 256, 0, stream>>>(
      wsu + o_H, wsu + o_qkvW, nullptr, nullptr, nullptr, wsu + o_Q, wsu + o_K, wsu + o_VT,
      8192, 3072, 1024, 768);

  attn_kernel<<<dim3(64, 16), 256, 0, stream>>>(wsu + o_Q, wsu + o_K, wsu + o_VT, wsu + o_ATT);

  // proj: 256 tiles (8x32)
  gemm8p<256, 128, 2, 2, 3, 256, 2><<<256, 256, 0, stream>>>(
      wsu + o_ATT, wsu + o_projW, bproj, x, out, nullptr, nullptr, nullptr,
      8192, 1024, 1024, 256);

  ln_kernel<<<2048, 256, 0, stream>>>(out, g2, beta2, wsu + o_H);

  // FF1: 512 tiles (16x32)
  gemm8p<256, 256, 2, 4, 4, 512, 1><<<512, 512, 0, stream>>>(
      wsu + o_H, wsu + o_W1, b1, nullptr, nullptr, wsu + o_FF1, nullptr, nullptr,
      8192, 4096, 1024, 512);

  // FF2: 256 tiles (8x32), K=4096
  gemm8p<256, 128, 2, 2, 3, 256, 2><<<256, 256, 0, stream>>>(
      wsu + o_FF1, wsu + o_W2, b2, out, out, nullptr, nullptr, nullptr,
      8192, 1024, 4096, 256);
}